// Round 5
// baseline (1664.378 us; speedup 1.0000x reference)
//
#include <hip/hip_runtime.h>
#include <hip/hip_bf16.h>
#include <math.h>

#define BB 4
#define TT 512
#define SDIM 64
#define ADIM 32
#define HDIM 512
#define NH 8
#define NBLK 6
#define DFF 2048
#define SS 1536          // 3*T
#define DH 64
#define MS (BB*SS)       // 6144 rows

typedef __attribute__((ext_vector_type(8))) __bf16 bf16x8;
typedef __attribute__((ext_vector_type(4))) float f32x4;

__device__ __forceinline__ __bf16 f2b(float x) { return (__bf16)x; }

// async global->LDS, 16 B per lane; LDS dest = wave-uniform base + lane*16
__device__ __forceinline__ void gll16(const void* g, void* l) {
    __builtin_amdgcn_global_load_lds(
        (const __attribute__((address_space(1))) unsigned int*)g,
        (__attribute__((address_space(3))) unsigned int*)l, 16, 0, 0);
}

// ================= shuffle-based LN over 512 threads =================
__device__ __forceinline__ float block_ln2(float val, int tid,
                                           const float* __restrict__ g,
                                           const float* __restrict__ bvec,
                                           float* red)
{
    float s = val, sq = val * val;
    #pragma unroll
    for (int off = 32; off; off >>= 1) { s += __shfl_xor(s, off); sq += __shfl_xor(sq, off); }
    int w = tid >> 6;
    if ((tid & 63) == 0) { red[w] = s; red[8 + w] = sq; }
    __syncthreads();
    float S = 0.f, SQ = 0.f;
    #pragma unroll
    for (int i = 0; i < 8; ++i) { S += red[i]; SQ += red[8 + i]; }
    float mean = S * (1.f / HDIM);
    float var  = SQ * (1.f / HDIM) - mean * mean;
    return (val - mean) * rsqrtf(var + 1e-5f) * g[tid] + bvec[tid];
}

// ================= embed + LN -> h (fp32) and h_bf (bf16) =================
__global__ __launch_bounds__(512) void embed_ln_kernel(
    const int* __restrict__ timesteps,
    const float* __restrict__ state0, const float* __restrict__ state1,
    const float* __restrict__ actions, const float* __restrict__ time_emb,
    const float* __restrict__ Ws, const float* __restrict__ bs,
    const float* __restrict__ Wa, const float* __restrict__ ba,
    const float* __restrict__ eg, const float* __restrict__ eb,
    float* __restrict__ h, __bf16* __restrict__ h_bf)
{
    __shared__ float xs[SDIM];
    __shared__ float red[16];
    int row = blockIdx.x;
    int b = row / SS;
    int pos = row - b * SS;
    int i = pos / 3;
    int t = pos - i * 3;
    int col = threadIdx.x;

    const float* x; const float* W; const float* bias; int K;
    if (t == 0)      { x = state0  + (size_t)(b*TT + i) * SDIM; W = Ws; bias = bs; K = SDIM; }
    else if (t == 1) { x = state1  + (size_t)(b*TT + i) * SDIM; W = Ws; bias = bs; K = SDIM; }
    else             { x = actions + (size_t)(b*TT + i) * ADIM; W = Wa; bias = ba; K = ADIM; }

    if (col < K) xs[col] = x[col];
    __syncthreads();

    int ts = timesteps[b*TT + i];
    float acc = bias[col] + time_emb[(size_t)ts * HDIM + col];
    for (int kk = 0; kk < K; ++kk)
        acc += xs[kk] * W[(size_t)kk * HDIM + col];

    float y = block_ln2(acc, col, eg, eb, red);
    h[(size_t)row * HDIM + col] = y;
    h_bf[(size_t)row * HDIM + col] = f2b(y);
}

// ================= residual add + LN =================
__global__ __launch_bounds__(512) void ln_add_kernel(
    float* __restrict__ h, const float* __restrict__ y,
    const float* __restrict__ g, const float* __restrict__ bvec,
    __bf16* __restrict__ h_bf)
{
    __shared__ float red[16];
    int row = blockIdx.x, col = threadIdx.x;
    float val = h[(size_t)row * HDIM + col] + y[(size_t)row * HDIM + col];
    float o = block_ln2(val, col, g, bvec, red);
    h[(size_t)row * HDIM + col] = o;
    h_bf[(size_t)row * HDIM + col] = f2b(o);
}

// ================= weight pack: fp32 [K][N] -> bf16 [N][K] =================
__global__ __launch_bounds__(256) void pack_kernel(
    const float* __restrict__ wq, const float* __restrict__ wk,
    const float* __restrict__ wv, const float* __restrict__ wo,
    const float* __restrict__ w1, const float* __restrict__ w2,
    const float* __restrict__ bq_, const float* __restrict__ bk_, const float* __restrict__ bv_,
    __bf16* __restrict__ wqkvT, __bf16* __restrict__ woT,
    __bf16* __restrict__ w1T, __bf16* __restrict__ w2T, float* __restrict__ biasq)
{
    int bid = blockIdx.x;
    int tid = threadIdx.x;
    if (bid == 768) {
        for (int i = tid; i < 1536; i += 256)
            biasq[i] = (i < 512) ? bq_[i] : ((i < 1024) ? bk_[i-512] : bv_[i-1024]);
        return;
    }
    __shared__ float Ls[64][65];
    const float* src; __bf16* dst; int K, N, kt, nt;
    if (bid < 192) {
        int sec = bid / 64, t = bid % 64;
        src = (sec == 0) ? wq : (sec == 1) ? wk : wv;
        dst = wqkvT + (size_t)sec * 512 * 512;
        K = 512; N = 512; nt = t >> 3; kt = t & 7;
    } else if (bid < 256) {
        int t = bid - 192; src = wo; dst = woT; K = 512; N = 512; nt = t >> 3; kt = t & 7;
    } else if (bid < 512) {
        int t = bid - 256; src = w1; dst = w1T; K = 512; N = 2048; nt = t >> 3; kt = t & 7;
    } else {
        int t = bid - 512; src = w2; dst = w2T; K = 2048; N = 512; nt = t & 7; kt = t >> 3;
    }
    int k0 = kt * 64, n0 = nt * 64;
    int rr = tid >> 4, cc = (tid & 15) * 4;
    #pragma unroll
    for (int p = 0; p < 4; ++p) {
        float4 v = *(const float4*)(src + (size_t)(k0 + rr + p*16) * N + n0 + cc);
        Ls[rr + p*16][cc] = v.x; Ls[rr + p*16][cc+1] = v.y;
        Ls[rr + p*16][cc+2] = v.z; Ls[rr + p*16][cc+3] = v.w;
    }
    __syncthreads();
    int nn = tid >> 3, kc = (tid & 7) * 8;
    #pragma unroll
    for (int p = 0; p < 2; ++p) {
        __bf16 t8[8];
        #pragma unroll
        for (int t2 = 0; t2 < 8; ++t2) t8[t2] = f2b(Ls[kc + t2][nn + p*32]);
        *(uint4*)(dst + (size_t)(n0 + nn + p*32) * K + k0 + kc) = *(uint4*)t8;
    }
}

// ================= V transpose: qkv v-section -> VT[(b*NH+h)*64+d][s] =================
__global__ __launch_bounds__(256) void vtrans_kernel(
    const __bf16* __restrict__ qkv, __bf16* __restrict__ VT)
{
    __shared__ __bf16 Ls[64][72];
    int dt = blockIdx.x;          // 0..7 (head)
    int st = blockIdx.y;          // 0..95
    int s0 = st * 64;
    int b  = s0 / SS;
    int srel = s0 - b * SS;
    int tid = threadIdx.x;
    int r = tid >> 3, ch = tid & 7;
    #pragma unroll
    for (int p = 0; p < 2; ++p) {
        uint4 v = *(const uint4*)(qkv + (size_t)(s0 + r + p*32) * 1536 + 1024 + dt*64 + ch*8);
        *(uint4*)&Ls[r + p*32][ch*8] = v;
    }
    __syncthreads();
    int dd = tid >> 3;
    #pragma unroll
    for (int p = 0; p < 2; ++p) {
        __bf16 t8[8];
        #pragma unroll
        for (int t2 = 0; t2 < 8; ++t2) t8[t2] = Ls[ch*8 + t2][dd + p*32];
        *(uint4*)(VT + ((size_t)(b*NH + dt) * 64 + dd + p*32) * SS + srel + ch*8) = *(uint4*)t8;
    }
}

// ================= bf16 MFMA GEMM with async LDS staging =================
// A: bf16 row-major MxK.  Bt: bf16 [N][K].  flags: 1 = bf16 out, 2 = gelu.
// LDS rows are 32 bf16 (4 chunks of 16 B); chunk c of row r is stored at
// physical chunk c ^ ((r>>1)&3) so global_load_lds (lane*16 fixed dest) and
// conflict-free ds_read_b128 coexist without padding.
template<int MT>
__global__ __launch_bounds__(256) void gemm_mfma(
    const __bf16* __restrict__ A, const __bf16* __restrict__ Bt,
    const float* __restrict__ bias, void* __restrict__ Cout,
    int M, int N, int K, int flags)
{
    constexpr int MI = MT / 32;          // A-frags per wave (row dim)
    __shared__ __bf16 As[MT][32];
    __shared__ __bf16 Bs[128][32];
    int tid = threadIdx.x;
    int wave = tid >> 6, lane = tid & 63;
    int l15 = lane & 15, quad = lane >> 4;
    int wy = wave >> 1, wx = wave & 1;
    int m0 = blockIdx.y * MT, n0 = blockIdx.x * 128;

    // staging source mapping for this lane
    int srow = lane >> 2;                        // 0..15 within issue
    int clog = (lane & 3) ^ ((lane >> 3) & 3);   // logical k-chunk (8 bf16)
    // frag-read physical chunk for this lane
    int pchunk = (quad ^ ((l15 >> 1) & 3)) * 8;

    f32x4 acc[MI][4];
    #pragma unroll
    for (int i = 0; i < MI; ++i)
        #pragma unroll
        for (int j = 0; j < 4; ++j) acc[i][j] = (f32x4){0.f,0.f,0.f,0.f};

    for (int k0 = 0; k0 < K; k0 += 32) {
        // A tile: MT rows; MT/64 issues per wave
        #pragma unroll
        for (int q = 0; q < MT/64; ++q) {
            int r0 = (wave * (MT/64) + q) * 16;
            gll16(A + (size_t)(m0 + r0 + srow) * K + k0 + clog * 8, &As[r0][0]);
        }
        // B tile: 128 rows; 2 issues per wave
        #pragma unroll
        for (int q = 0; q < 2; ++q) {
            int r0 = (wave * 2 + q) * 16;
            gll16(Bt + (size_t)(n0 + r0 + srow) * K + k0 + clog * 8, &Bs[r0][0]);
        }
        __syncthreads();          // drains vmcnt -> LDS populated

        bf16x8 af[MI], bf[4];
        #pragma unroll
        for (int i = 0; i < MI; ++i) af[i] = *(const bf16x8*)&As[wy*(MT/2) + i*16 + l15][pchunk];
        #pragma unroll
        for (int j = 0; j < 4; ++j)  bf[j] = *(const bf16x8*)&Bs[wx*64 + j*16 + l15][pchunk];
        #pragma unroll
        for (int i = 0; i < MI; ++i)
            #pragma unroll
            for (int j = 0; j < 4; ++j)
                acc[i][j] = __builtin_amdgcn_mfma_f32_16x16x32_bf16(af[i], bf[j], acc[i][j], 0, 0, 0);
        __syncthreads();          // protect LDS from next iteration's staging
    }

    float* Cf = (float*)Cout;
    __bf16* Cb = (__bf16*)Cout;
    int obf = flags & 1, gel = flags & 2;
    #pragma unroll
    for (int j = 0; j < 4; ++j) {
        int cc = n0 + wx*64 + j*16 + l15;
        float bv = bias[cc];
        #pragma unroll
        for (int i = 0; i < MI; ++i) {
            #pragma unroll
            for (int r = 0; r < 4; ++r) {
                int rr = m0 + wy*(MT/2) + i*16 + quad*4 + r;
                float v = acc[i][j][r] + bv;
                if (gel) v = 0.5f * v * (1.f + erff(v * 0.70710678118654752f));
                if (obf) Cb[(size_t)rr * N + cc] = f2b(v);
                else     Cf[(size_t)rr * N + cc] = v;
            }
        }
    }
}

// ================= S^T-layout MFMA flash attention (reg-resident softmax) =================
#define SM_C 0.18033688011112042f   // (1/8) * log2(e)

struct KVfrags { bf16x8 k00, k01, k10, k11, v0, v1, v2, v3; };

__device__ __forceinline__ KVfrags load_kv(const __bf16* kp, const __bf16* vp, int kb)
{
    KVfrags f;
    f.k00 = *(const bf16x8*)(kp + (size_t)kb * 1536);
    f.k01 = *(const bf16x8*)(kp + (size_t)kb * 1536 + 32);
    f.k10 = *(const bf16x8*)(kp + (size_t)(kb + 16) * 1536);
    f.k11 = *(const bf16x8*)(kp + (size_t)(kb + 16) * 1536 + 32);
    f.v0  = *(const bf16x8*)(vp + kb);
    f.v1  = *(const bf16x8*)(vp + (size_t)16 * SS + kb);
    f.v2  = *(const bf16x8*)(vp + (size_t)32 * SS + kb);
    f.v3  = *(const bf16x8*)(vp + (size_t)48 * SS + kb);
    return f;
}

__device__ __forceinline__ unsigned pack2bf(float a, float b)
{
    union { __bf16 h[2]; unsigned u; } t;
    t.h[0] = (__bf16)a; t.h[1] = (__bf16)b;
    return t.u;
}

struct AttnState {
    f32x4 o0, o1, o2, o3;
    float m, l;
};

__device__ __forceinline__ void attn_step(AttnState& st, const KVfrags& kv,
                                          bf16x8 qf0, bf16x8 qf1,
                                          int kb, int qrow0, int lane)
{
    int l15 = lane & 15, quad = lane >> 4;
    f32x4 s0 = {0.f,0.f,0.f,0.f}, s1 = {0.f,0.f,0.f,0.f};
    s0 = __builtin_amdgcn_mfma_f32_16x16x32_bf16(kv.k00, qf0, s0, 0, 0, 0);
    s0 = __builtin_amdgcn_mfma_f32_16x16x32_bf16(kv.k01, qf1, s0, 0, 0, 0);
    s1 = __builtin_amdgcn_mfma_f32_16x16x32_bf16(kv.k10, qf0, s1, 0, 0, 0);
    s1 = __builtin_amdgcn_mfma_f32_16x16x32_bf16(kv.k11, qf1, s1, 0, 0, 0);

    if (kb + 31 > qrow0) {          // wave-uniform: tile straddles diagonal
        int qrow = qrow0 + l15;
        #pragma unroll
        for (int r = 0; r < 4; ++r) {
            int c0 = kb + quad*4 + r;
            if (c0 > qrow)      s0[r] = -1e30f;
            if (c0 + 16 > qrow) s1[r] = -1e30f;
        }
    }

    float tm = fmaxf(fmaxf(fmaxf(s0[0], s0[1]), fmaxf(s0[2], s0[3])),
                     fmaxf(fmaxf(s1[0], s1[1]), fmaxf(s1[2], s1[3])));
    tm = fmaxf(tm, __shfl_xor(tm, 16));
    tm = fmaxf(tm, __shfl_xor(tm, 32));
    float mnew = fmaxf(st.m, tm);
    float alpha = __builtin_amdgcn_exp2f((st.m - mnew) * SM_C);

    float p0[4], p1[4], rs = 0.f;
    #pragma unroll
    for (int r = 0; r < 4; ++r) {
        p0[r] = __builtin_amdgcn_exp2f((s0[r] - mnew) * SM_C);
        p1[r] = __builtin_amdgcn_exp2f((s1[r] - mnew) * SM_C);
        rs += p0[r] + p1[r];
    }
    rs += __shfl_xor(rs, 16);
    rs += __shfl_xor(rs, 32);
    st.l = st.l * alpha + rs;
    st.m = mnew;
    st.o0 *= alpha; st.o1 *= alpha; st.o2 *= alpha; st.o3 *= alpha;

    // P^T -> PV B-frag. ALL shuffles execute unconditionally at full wave
    // exec; per-lane selection via v_cndmask on the shuffled results.
    unsigned pk0a = pack2bf(p0[0], p0[1]), pk0b = pack2bf(p0[2], p0[3]);
    unsigned pk1a = pack2bf(p1[0], p1[1]), pk1b = pack2bf(p1[2], p1[3]);
    int sA = l15 + (quad & 1) * 32;
    int sB = sA + 16;
    int hi = quad >> 1;
    unsigned a0A = (unsigned)__shfl((int)pk0a, sA);
    unsigned a1A = (unsigned)__shfl((int)pk1a, sA);
    unsigned b0A = (unsigned)__shfl((int)pk0b, sA);
    unsigned b1A = (unsigned)__shfl((int)pk1b, sA);
    unsigned a0B = (unsigned)__shfl((int)pk0a, sB);
    unsigned a1B = (unsigned)__shfl((int)pk1a, sB);
    unsigned b0B = (unsigned)__shfl((int)pk0b, sB);
    unsigned b1B = (unsigned)__shfl((int)pk1b, sB);
    union { unsigned u[4]; bf16x8 v; } pb;
    pb.u[0] = hi ? a1A : a0A;
    pb.u[1] = hi ? b1A : b0A;
    pb.u[2] = hi ? a1B : a0B;
    pb.u[3] = hi ? b1B : b0B;

    st.o0 = __builtin_amdgcn_mfma_f32_16x16x32_bf16(kv.v0, pb.v, st.o0, 0, 0, 0);
    st.o1 = __builtin_amdgcn_mfma_f32_16x16x32_bf16(kv.v1, pb.v, st.o1, 0, 0, 0);
    st.o2 = __builtin_amdgcn_mfma_f32_16x16x32_bf16(kv.v2, pb.v, st.o2, 0, 0, 0);
    st.o3 = __builtin_amdgcn_mfma_f32_16x16x32_bf16(kv.v3, pb.v, st.o3, 0, 0, 0);
}

// grid: flat 3072 one-wave blocks; g = 16-row Q chunk index (0..95),
// light/heavy pair-interleaved for load balance.
__global__ __launch_bounds__(64, 4) void attn_kernel(
    const __bf16* __restrict__ qkv, const __bf16* __restrict__ VT,
    __bf16* __restrict__ ctx)
{
    __shared__ float ot[16][68];
    int x = blockIdx.x;
    int i = x >> 5;               // 0..95
    int hb = x & 31;
    int g = (i & 1) ? (95 - (i >> 1)) : (i >> 1);
    int h = hb >> 2, b = hb & 3;

    int lane = threadIdx.x;       // one wave
    int l15 = lane & 15, quad = lane >> 4;
    int qrow0 = g * 16;

    const __bf16* qp = qkv + (size_t)(b*SS + qrow0 + l15) * 1536 + h*64 + quad*8;
    bf16x8 qf0 = *(const bf16x8*)qp;
    bf16x8 qf1 = *(const bf16x8*)(qp + 32);

    const __bf16* kp = qkv + (size_t)(b*SS + l15) * 1536 + 512 + h*64 + quad*8;
    const __bf16* vp = VT + ((size_t)(b*NH + h) * 64 + l15) * SS + quad*8;

    AttnState st;
    st.o0 = (f32x4){0.f,0.f,0.f,0.f}; st.o1 = st.o0; st.o2 = st.o0; st.o3 = st.o0;
    st.m = -1e30f; st.l = 0.f;

    int nkt = (qrow0 + 47) >> 5;

    KVfrags ka = load_kv(kp, vp, 0);
    for (int jt = 0; jt < nkt; ) {
        KVfrags kb2;
        bool h1 = (jt + 1) < nkt;
        if (h1) kb2 = load_kv(kp, vp, (jt + 1) * 32);
        attn_step(st, ka, qf0, qf1, jt * 32, qrow0, lane);
        ++jt;
        if (!h1) break;
        if ((jt + 1) < nkt) ka = load_kv(kp, vp, (jt + 1) * 32);
        attn_step(st, kb2, qf0, qf1, jt * 32, qrow0, lane);
        ++jt;
    }

    // epilogue: O^T regs -> LDS -> coalesced bf16 stores
    float inv = 1.f / st.l;
    #pragma unroll
    for (int r = 0; r < 4; ++r) {
        ot[l15][ 0 + quad*4 + r] = st.o0[r] * inv;
        ot[l15][16 + quad*4 + r] = st.o1[r] * inv;
        ot[l15][32 + quad*4 + r] = st.o2[r] * inv;
        ot[l15][48 + quad*4 + r] = st.o3[r] * inv;
    }
    asm volatile("s_waitcnt lgkmcnt(0)" ::: "memory");
    int row = lane >> 2, ch = (lane & 3) * 16;
    union { __bf16 hh[16]; uint4 q4[2]; } ob;
    #pragma unroll
    for (int t2 = 0; t2 < 16; ++t2) ob.hh[t2] = f2b(ot[row][ch + t2]);
    __bf16* cp = ctx + (size_t)(b*SS + qrow0 + row) * 512 + h*64 + ch;
    *(uint4*)cp = ob.q4[0];
    *(uint4*)(cp + 8) = ob.q4[1];
}

// ================= final projection =================
__global__ __launch_bounds__(256) void proj_kernel(
    const float* __restrict__ h, const float* __restrict__ Wp,
    const float* __restrict__ bp, float* __restrict__ out)
{
    int rid = blockIdx.x * 8 + (threadIdx.x >> 5);
    int col = threadIdx.x & 31;
    int b = rid / TT, i = rid - b * TT;
    const float* x = h + ((size_t)(b*SS) + 3*i + 1) * HDIM;
    float acc = bp[col];
    for (int kk = 0; kk < HDIM; ++kk)
        acc += x[kk] * Wp[kk * ADIM + col];
    out[(size_t)rid * ADIM + col] = acc;
}

extern "C" void kernel_launch(void* const* d_in, const int* in_sizes, int n_in,
                              void* d_out, int out_size, void* d_ws, size_t ws_size,
                              hipStream_t stream)
{
    (void)in_sizes; (void)n_in; (void)out_size; (void)ws_size;
    const int*   timesteps = (const int*)  d_in[0];
    const float* state0    = (const float*)d_in[1];
    const float* state1    = (const float*)d_in[2];
    const float* actions   = (const float*)d_in[3];
    const float* time_emb  = (const float*)d_in[4];
    const float* Ws  = (const float*)d_in[5];
    const float* bs  = (const float*)d_in[6];
    const float* Wa  = (const float*)d_in[7];
    const float* ba  = (const float*)d_in[8];
    const float* Wq  = (const float*)d_in[9];
    const float* bq  = (const float*)d_in[10];
    const float* Wk  = (const float*)d_in[11];
    const float* bk  = (const float*)d_in[12];
    const float* Wv  = (const float*)d_in[13];
    const float* bv  = (const float*)d_in[14];
    const float* Wo  = (const float*)d_in[15];
    const float* bo  = (const float*)d_in[16];
    const float* W1  = (const float*)d_in[17];
    const float* b1  = (const float*)d_in[18];
    const float* W2  = (const float*)d_in[19];
    const float* b2  = (const float*)d_in[20];
    const float* ln1g = (const float*)d_in[21];
    const float* ln1b = (const float*)d_in[22];
    const float* ln2g = (const float*)d_in[23];
    const float* ln2b = (const float*)d_in[24];
    const float* elng = (const float*)d_in[25];
    const float* elnb = (const float*)d_in[26];
    const float* Wp   = (const float*)d_in[27];
    const float* bp   = (const float*)d_in[28];
    float* out = (float*)d_out;

    const size_t SZ = (size_t)MS * HDIM;          // 3,145,728
    char* p = (char*)d_ws;
    float*  h    = (float*)p;            p += SZ * 4;
    float*  tmp  = (float*)p;            p += SZ * 4;
    __bf16* h_bf = (__bf16*)p;           p += SZ * 2;
    __bf16* qkv  = (__bf16*)p;           p += SZ * 3 * 2;
    __bf16* ctx  = (__bf16*)p;           p += SZ * 2;
    __bf16* VT   = (__bf16*)p;           p += SZ * 2;
    __bf16* wqkvT = (__bf16*)p;          p += (size_t)1536 * 512 * 2;
    __bf16* woT   = (__bf16*)p;          p += (size_t)512 * 512 * 2;
    __bf16* w1T   = (__bf16*)p;          p += (size_t)2048 * 512 * 2;
    __bf16* w2T   = (__bf16*)p;          p += (size_t)512 * 2048 * 2;
    float*  biasq = (float*)p;           p += 1536 * 4;
    __bf16* hid  = qkv;                  // MS x DFF bf16, aliases qkv+ctx

    embed_ln_kernel<<<MS, 512, 0, stream>>>(timesteps, state0, state1, actions, time_emb,
                                            Ws, bs, Wa, ba, elng, elnb, h, h_bf);

    dim3 gQKV(1536/128, MS/128);   // 12 x 48
    dim3 gO  (512/128,  MS/64);    // 4 x 96  (64-row tiles)
    dim3 gF1 (2048/128, MS/128);   // 16 x 48
    dim3 gV  (NH, MS/64);          // 8 x 96

    for (int lyr = 0; lyr < NBLK; ++lyr) {
        const float* wq = Wq + (size_t)lyr * HDIM * HDIM;
        const float* wk = Wk + (size_t)lyr * HDIM * HDIM;
        const float* wv = Wv + (size_t)lyr * HDIM * HDIM;
        const float* wo = Wo + (size_t)lyr * HDIM * HDIM;
        const float* w1 = W1 + (size_t)lyr * HDIM * DFF;
        const float* w2 = W2 + (size_t)lyr * DFF * HDIM;

        pack_kernel<<<769, 256, 0, stream>>>(wq, wk, wv, wo, w1, w2,
                                             bq + lyr*HDIM, bk + lyr*HDIM, bv + lyr*HDIM,
                                             wqkvT, woT, w1T, w2T, biasq);
        gemm_mfma<128><<<gQKV, 256, 0, stream>>>(h_bf, wqkvT, biasq, qkv, MS, 1536, HDIM, 1);
        vtrans_kernel<<<gV, 256, 0, stream>>>(qkv, VT);
        attn_kernel<<<dim3(3072), 64, 0, stream>>>(qkv, VT, ctx);
        gemm_mfma<64><<<gO, 256, 0, stream>>>(ctx, woT, bo + lyr*HDIM, tmp, MS, HDIM, HDIM, 0);
        ln_add_kernel<<<MS, 512, 0, stream>>>(h, tmp, ln1g + lyr*HDIM, ln1b + lyr*HDIM, h_bf);
        gemm_mfma<128><<<gF1, 256, 0, stream>>>(h_bf, w1T, b1 + lyr*DFF, hid, MS, DFF, HDIM, 1 | 2);
        gemm_mfma<64><<<gO, 256, 0, stream>>>(hid, w2T, b2 + lyr*HDIM, tmp, MS, HDIM, DFF, 0);
        ln_add_kernel<<<MS, 512, 0, stream>>>(h, tmp, ln2g + lyr*HDIM, ln2b + lyr*HDIM, h_bf);
    }

    proj_kernel<<<(BB*TT)/8, 256, 0, stream>>>(h, Wp, bp, out);
}

// Round 7
// 1268.096 us; speedup vs baseline: 1.3125x; 1.3125x over previous
//
#include <hip/hip_runtime.h>
#include <hip/hip_bf16.h>
#include <math.h>

#define BB 4
#define TT 512
#define SDIM 64
#define ADIM 32
#define HDIM 512
#define NH 8
#define NBLK 6
#define DFF 2048
#define SS 1536          // 3*T
#define DH 64
#define MS (BB*SS)       // 6144 rows

typedef __attribute__((ext_vector_type(8))) __bf16 bf16x8;
typedef __attribute__((ext_vector_type(4))) float f32x4;

__device__ __forceinline__ __bf16 f2b(float x) { return (__bf16)x; }

// async global->LDS, 16 B per lane; LDS dest = wave-uniform base + lane*16
__device__ __forceinline__ void gll16(const void* g, void* l) {
    __builtin_amdgcn_global_load_lds(
        (const __attribute__((address_space(1))) unsigned int*)g,
        (__attribute__((address_space(3))) unsigned int*)l, 16, 0, 0);
}

// ================= shuffle-based LN over 512 threads =================
__device__ __forceinline__ float block_ln2(float val, int tid,
                                           const float* __restrict__ g,
                                           const float* __restrict__ bvec,
                                           float* red)
{
    float s = val, sq = val * val;
    #pragma unroll
    for (int off = 32; off; off >>= 1) { s += __shfl_xor(s, off); sq += __shfl_xor(sq, off); }
    int w = tid >> 6;
    if ((tid & 63) == 0) { red[w] = s; red[8 + w] = sq; }
    __syncthreads();
    float S = 0.f, SQ = 0.f;
    #pragma unroll
    for (int i = 0; i < 8; ++i) { S += red[i]; SQ += red[8 + i]; }
    float mean = S * (1.f / HDIM);
    float var  = SQ * (1.f / HDIM) - mean * mean;
    return (val - mean) * rsqrtf(var + 1e-5f) * g[tid] + bvec[tid];
}

// ================= embed + LN -> h (fp32) and h_bf (bf16) =================
__global__ __launch_bounds__(512) void embed_ln_kernel(
    const int* __restrict__ timesteps,
    const float* __restrict__ state0, const float* __restrict__ state1,
    const float* __restrict__ actions, const float* __restrict__ time_emb,
    const float* __restrict__ Ws, const float* __restrict__ bs,
    const float* __restrict__ Wa, const float* __restrict__ ba,
    const float* __restrict__ eg, const float* __restrict__ eb,
    float* __restrict__ h, __bf16* __restrict__ h_bf)
{
    __shared__ float xs[SDIM];
    __shared__ float red[16];
    int row = blockIdx.x;
    int b = row / SS;
    int pos = row - b * SS;
    int i = pos / 3;
    int t = pos - i * 3;
    int col = threadIdx.x;

    const float* x; const float* W; const float* bias; int K;
    if (t == 0)      { x = state0  + (size_t)(b*TT + i) * SDIM; W = Ws; bias = bs; K = SDIM; }
    else if (t == 1) { x = state1  + (size_t)(b*TT + i) * SDIM; W = Ws; bias = bs; K = SDIM; }
    else             { x = actions + (size_t)(b*TT + i) * ADIM; W = Wa; bias = ba; K = ADIM; }

    if (col < K) xs[col] = x[col];
    __syncthreads();

    int ts = timesteps[b*TT + i];
    float acc = bias[col] + time_emb[(size_t)ts * HDIM + col];
    for (int kk = 0; kk < K; ++kk)
        acc += xs[kk] * W[(size_t)kk * HDIM + col];

    float y = block_ln2(acc, col, eg, eb, red);
    h[(size_t)row * HDIM + col] = y;
    h_bf[(size_t)row * HDIM + col] = f2b(y);
}

// ================= residual add + LN (y in bf16) =================
__global__ __launch_bounds__(512) void ln_add_kernel(
    float* __restrict__ h, const __bf16* __restrict__ y,
    const float* __restrict__ g, const float* __restrict__ bvec,
    __bf16* __restrict__ h_bf)
{
    __shared__ float red[16];
    int row = blockIdx.x, col = threadIdx.x;
    float val = h[(size_t)row * HDIM + col] + (float)y[(size_t)row * HDIM + col];
    float o = block_ln2(val, col, g, bvec, red);
    h[(size_t)row * HDIM + col] = o;
    h_bf[(size_t)row * HDIM + col] = f2b(o);
}

// ================= weight pack: fp32 [K][N] -> bf16 [N][K] =================
__global__ __launch_bounds__(256) void pack_kernel(
    const float* __restrict__ wq, const float* __restrict__ wk,
    const float* __restrict__ wv, const float* __restrict__ wo,
    const float* __restrict__ w1, const float* __restrict__ w2,
    const float* __restrict__ bq_, const float* __restrict__ bk_, const float* __restrict__ bv_,
    __bf16* __restrict__ wqkvT, __bf16* __restrict__ woT,
    __bf16* __restrict__ w1T, __bf16* __restrict__ w2T, float* __restrict__ biasq)
{
    int bid = blockIdx.x;
    int tid = threadIdx.x;
    if (bid == 768) {
        for (int i = tid; i < 1536; i += 256)
            biasq[i] = (i < 512) ? bq_[i] : ((i < 1024) ? bk_[i-512] : bv_[i-1024]);
        return;
    }
    __shared__ float Ls[64][65];
    const float* src; __bf16* dst; int K, N, kt, nt;
    if (bid < 192) {
        int sec = bid / 64, t = bid % 64;
        src = (sec == 0) ? wq : (sec == 1) ? wk : wv;
        dst = wqkvT + (size_t)sec * 512 * 512;
        K = 512; N = 512; nt = t >> 3; kt = t & 7;
    } else if (bid < 256) {
        int t = bid - 192; src = wo; dst = woT; K = 512; N = 512; nt = t >> 3; kt = t & 7;
    } else if (bid < 512) {
        int t = bid - 256; src = w1; dst = w1T; K = 512; N = 2048; nt = t >> 3; kt = t & 7;
    } else {
        int t = bid - 512; src = w2; dst = w2T; K = 2048; N = 512; nt = t & 7; kt = t >> 3;
    }
    int k0 = kt * 64, n0 = nt * 64;
    int rr = tid >> 4, cc = (tid & 15) * 4;
    #pragma unroll
    for (int p = 0; p < 4; ++p) {
        float4 v = *(const float4*)(src + (size_t)(k0 + rr + p*16) * N + n0 + cc);
        Ls[rr + p*16][cc] = v.x; Ls[rr + p*16][cc+1] = v.y;
        Ls[rr + p*16][cc+2] = v.z; Ls[rr + p*16][cc+3] = v.w;
    }
    __syncthreads();
    int nn = tid >> 3, kc = (tid & 7) * 8;
    #pragma unroll
    for (int p = 0; p < 2; ++p) {
        __bf16 t8[8];
        #pragma unroll
        for (int t2 = 0; t2 < 8; ++t2) t8[t2] = f2b(Ls[kc + t2][nn + p*32]);
        *(uint4*)(dst + (size_t)(n0 + nn + p*32) * K + k0 + kc) = *(uint4*)t8;
    }
}

// ================= V transpose: qkv v-section -> VT[(b*NH+h)*64+d][s] =================
__global__ __launch_bounds__(256) void vtrans_kernel(
    const __bf16* __restrict__ qkv, __bf16* __restrict__ VT)
{
    __shared__ __bf16 Ls[64][72];
    int dt = blockIdx.x;          // 0..7 (head)
    int st = blockIdx.y;          // 0..95
    int s0 = st * 64;
    int b  = s0 / SS;
    int srel = s0 - b * SS;
    int tid = threadIdx.x;
    int r = tid >> 3, ch = tid & 7;
    #pragma unroll
    for (int p = 0; p < 2; ++p) {
        uint4 v = *(const uint4*)(qkv + (size_t)(s0 + r + p*32) * 1536 + 1024 + dt*64 + ch*8);
        *(uint4*)&Ls[r + p*32][ch*8] = v;
    }
    __syncthreads();
    int dd = tid >> 3;
    #pragma unroll
    for (int p = 0; p < 2; ++p) {
        __bf16 t8[8];
        #pragma unroll
        for (int t2 = 0; t2 < 8; ++t2) t8[t2] = Ls[ch*8 + t2][dd + p*32];
        *(uint4*)(VT + ((size_t)(b*NH + dt) * 64 + dd + p*32) * SS + srel + ch*8) = *(uint4*)t8;
    }
}

// ================= bf16 MFMA GEMM with async LDS staging =================
template<int MT>
__global__ __launch_bounds__(256) void gemm_mfma(
    const __bf16* __restrict__ A, const __bf16* __restrict__ Bt,
    const float* __restrict__ bias, void* __restrict__ Cout,
    int M, int N, int K, int flags)
{
    constexpr int MI = MT / 32;
    __shared__ __bf16 As[MT][32];
    __shared__ __bf16 Bs[128][32];
    int tid = threadIdx.x;
    int wave = tid >> 6, lane = tid & 63;
    int l15 = lane & 15, quad = lane >> 4;
    int wy = wave >> 1, wx = wave & 1;
    int m0 = blockIdx.y * MT, n0 = blockIdx.x * 128;

    int srow = lane >> 2;
    int clog = (lane & 3) ^ ((lane >> 3) & 3);
    int pchunk = (quad ^ ((l15 >> 1) & 3)) * 8;

    f32x4 acc[MI][4];
    #pragma unroll
    for (int i = 0; i < MI; ++i)
        #pragma unroll
        for (int j = 0; j < 4; ++j) acc[i][j] = (f32x4){0.f,0.f,0.f,0.f};

    for (int k0 = 0; k0 < K; k0 += 32) {
        #pragma unroll
        for (int q = 0; q < MT/64; ++q) {
            int r0 = (wave * (MT/64) + q) * 16;
            gll16(A + (size_t)(m0 + r0 + srow) * K + k0 + clog * 8, &As[r0][0]);
        }
        #pragma unroll
        for (int q = 0; q < 2; ++q) {
            int r0 = (wave * 2 + q) * 16;
            gll16(Bt + (size_t)(n0 + r0 + srow) * K + k0 + clog * 8, &Bs[r0][0]);
        }
        __syncthreads();

        bf16x8 af[MI], bf[4];
        #pragma unroll
        for (int i = 0; i < MI; ++i) af[i] = *(const bf16x8*)&As[wy*(MT/2) + i*16 + l15][pchunk];
        #pragma unroll
        for (int j = 0; j < 4; ++j)  bf[j] = *(const bf16x8*)&Bs[wx*64 + j*16 + l15][pchunk];
        #pragma unroll
        for (int i = 0; i < MI; ++i)
            #pragma unroll
            for (int j = 0; j < 4; ++j)
                acc[i][j] = __builtin_amdgcn_mfma_f32_16x16x32_bf16(af[i], bf[j], acc[i][j], 0, 0, 0);
        __syncthreads();
    }

    float* Cf = (float*)Cout;
    __bf16* Cb = (__bf16*)Cout;
    int obf = flags & 1, gel = flags & 2;
    #pragma unroll
    for (int j = 0; j < 4; ++j) {
        int cc = n0 + wx*64 + j*16 + l15;
        float bv = bias[cc];
        #pragma unroll
        for (int i = 0; i < MI; ++i) {
            #pragma unroll
            for (int r = 0; r < 4; ++r) {
                int rr = m0 + wy*(MT/2) + i*16 + quad*4 + r;
                float v = acc[i][j][r] + bv;
                if (gel) v = 0.5f * v * (1.f + erff(v * 0.70710678118654752f));
                if (obf) Cb[(size_t)rr * N + cc] = f2b(v);
                else     Cf[(size_t)rr * N + cc] = v;
            }
        }
    }
}

// ================= S^T-layout MFMA flash attention, LDS-shared K/V =================
#define SM_C 0.18033688011112042f   // (1/8) * log2(e)

struct KVfrags { bf16x8 k00, k01, k10, k11, v0, v1, v2, v3; };

__device__ __forceinline__ unsigned pack2bf(float a, float b)
{
    union { __bf16 h[2]; unsigned u; } t;
    t.h[0] = (__bf16)a; t.h[1] = (__bf16)b;
    return t.u;
}

struct AttnState {
    f32x4 o0, o1, o2, o3;
    float m, l;
};

__device__ __forceinline__ void attn_step(AttnState& st, const KVfrags& kv,
                                          bf16x8 qf0, bf16x8 qf1,
                                          int kb, int qrow0, int lane)
{
    int l15 = lane & 15, quad = lane >> 4;
    f32x4 s0 = {0.f,0.f,0.f,0.f}, s1 = {0.f,0.f,0.f,0.f};
    s0 = __builtin_amdgcn_mfma_f32_16x16x32_bf16(kv.k00, qf0, s0, 0, 0, 0);
    s0 = __builtin_amdgcn_mfma_f32_16x16x32_bf16(kv.k01, qf1, s0, 0, 0, 0);
    s1 = __builtin_amdgcn_mfma_f32_16x16x32_bf16(kv.k10, qf0, s1, 0, 0, 0);
    s1 = __builtin_amdgcn_mfma_f32_16x16x32_bf16(kv.k11, qf1, s1, 0, 0, 0);

    if (kb + 31 > qrow0) {          // wave-uniform: tile straddles diagonal
        int qrow = qrow0 + l15;
        #pragma unroll
        for (int r = 0; r < 4; ++r) {
            int c0 = kb + quad*4 + r;
            if (c0 > qrow)      s0[r] = -1e30f;
            if (c0 + 16 > qrow) s1[r] = -1e30f;
        }
    }

    float tm = fmaxf(fmaxf(fmaxf(s0[0], s0[1]), fmaxf(s0[2], s0[3])),
                     fmaxf(fmaxf(s1[0], s1[1]), fmaxf(s1[2], s1[3])));
    tm = fmaxf(tm, __shfl_xor(tm, 16));
    tm = fmaxf(tm, __shfl_xor(tm, 32));
    float mnew = fmaxf(st.m, tm);
    float alpha = __builtin_amdgcn_exp2f((st.m - mnew) * SM_C);

    float p0[4], p1[4], rs = 0.f;
    #pragma unroll
    for (int r = 0; r < 4; ++r) {
        p0[r] = __builtin_amdgcn_exp2f((s0[r] - mnew) * SM_C);
        p1[r] = __builtin_amdgcn_exp2f((s1[r] - mnew) * SM_C);
        rs += p0[r] + p1[r];
    }
    rs += __shfl_xor(rs, 16);
    rs += __shfl_xor(rs, 32);
    st.l = st.l * alpha + rs;
    st.m = mnew;
    st.o0 *= alpha; st.o1 *= alpha; st.o2 *= alpha; st.o3 *= alpha;

    // P^T -> PV B-frag; all shuffles at full wave exec, per-lane cndmask after.
    unsigned pk0a = pack2bf(p0[0], p0[1]), pk0b = pack2bf(p0[2], p0[3]);
    unsigned pk1a = pack2bf(p1[0], p1[1]), pk1b = pack2bf(p1[2], p1[3]);
    int sA = l15 + (quad & 1) * 32;
    int sB = sA + 16;
    int hi = quad >> 1;
    unsigned a0A = (unsigned)__shfl((int)pk0a, sA);
    unsigned a1A = (unsigned)__shfl((int)pk1a, sA);
    unsigned b0A = (unsigned)__shfl((int)pk0b, sA);
    unsigned b1A = (unsigned)__shfl((int)pk1b, sA);
    unsigned a0B = (unsigned)__shfl((int)pk0a, sB);
    unsigned a1B = (unsigned)__shfl((int)pk1a, sB);
    unsigned b0B = (unsigned)__shfl((int)pk0b, sB);
    unsigned b1B = (unsigned)__shfl((int)pk1b, sB);
    union { unsigned u[4]; bf16x8 v; } pb;
    pb.u[0] = hi ? a1A : a0A;
    pb.u[1] = hi ? b1A : b0A;
    pb.u[2] = hi ? a1B : a0B;
    pb.u[3] = hi ? b1B : b0B;

    st.o0 = __builtin_amdgcn_mfma_f32_16x16x32_bf16(kv.v0, pb.v, st.o0, 0, 0, 0);
    st.o1 = __builtin_amdgcn_mfma_f32_16x16x32_bf16(kv.v1, pb.v, st.o1, 0, 0, 0);
    st.o2 = __builtin_amdgcn_mfma_f32_16x16x32_bf16(kv.v2, pb.v, st.o2, 0, 0, 0);
    st.o3 = __builtin_amdgcn_mfma_f32_16x16x32_bf16(kv.v3, pb.v, st.o3, 0, 0, 0);
}

// grid: 768 blocks (balanced qt triples), 256 threads; block shares K/V via LDS.
// LDS (24 KB, double-buffered): K tile [32 s][64 d] (8 KB/buf) chunk-swizzled
// p = c ^ (row&7); V^T tile [64 d][32 s] (4 KB/buf) p = c ^ ((row>>1)&3).
__global__ __launch_bounds__(256, 3) void attn_kernel(
    const __bf16* __restrict__ qkv, const __bf16* __restrict__ VT,
    __bf16* __restrict__ ctx)
{
    __shared__ __align__(16) char smem[24576];

    int x = blockIdx.x;
    int region = x >> 8;          // 0,1,2
    int j = x & 255;
    int i = j >> 5;               // 0..7
    int hb = j & 31;
    int qt = (region == 0) ? i : (region == 1) ? (15 - i) : (16 + i);
    int h = hb >> 2, b = hb & 3;

    int tid = threadIdx.x;
    int w = tid >> 6, lane = tid & 63;
    int l15 = lane & 15, quad = lane >> 4;
    int qrow0 = qt * 64 + w * 16;

    const __bf16* qp = qkv + (size_t)(b*SS + qrow0 + l15) * 1536 + h*64 + quad*8;
    bf16x8 qf0 = *(const bf16x8*)qp;
    bf16x8 qf1 = *(const bf16x8*)(qp + 32);

    // staging bases
    const __bf16* kgbase = qkv + (size_t)(b*SS) * 1536 + 512 + h*64;     // + row*1536
    const __bf16* vgbase = VT + (size_t)(b*NH + h) * 64 * SS;            // + row*SS
    int ksrow = lane >> 3;                       // 0..7
    int kclog = (lane & 7) ^ ((lane >> 3) & 7);
    int vsrow = lane >> 2;                       // 0..15
    int vclog = (lane & 3) ^ ((lane >> 3) & 3);

    // frag-read swizzled chunk offsets
    int swkA = (quad ^ (l15 & 7)) * 8;
    int swkB = ((quad + 4) ^ (l15 & 7)) * 8;
    int swv  = (quad ^ ((l15 >> 1) & 3)) * 8;

    AttnState st;
    st.o0 = (f32x4){0.f,0.f,0.f,0.f}; st.o1 = st.o0; st.o2 = st.o0; st.o3 = st.o0;
    st.m = -1e30f; st.l = 0.f;

    int mynkt = (qrow0 + 47) >> 5;
    int nkt_max = 2*qt + 2;

    // stage tile 0 into buffer 0
    gll16(kgbase + (size_t)(w*8 + ksrow) * 1536 + kclog*8, (__bf16*)smem + (w*8)*64);
    gll16(vgbase + (size_t)(w*16 + vsrow) * SS + vclog*8,  (__bf16*)(smem + 16384) + (w*16)*32);
    __syncthreads();

    for (int jt = 0; jt < nkt_max; ++jt) {
        int buf = jt & 1;
        __bf16* Kb = (__bf16*)(smem + buf * 8192);
        __bf16* Vb = (__bf16*)(smem + 16384 + buf * 4096);
        __bf16* Kn = (__bf16*)(smem + (buf ^ 1) * 8192);
        __bf16* Vn = (__bf16*)(smem + 16384 + (buf ^ 1) * 4096);
        if (jt + 1 < nkt_max) {
            int kb = (jt + 1) * 32;
            gll16(kgbase + (size_t)(kb + w*8 + ksrow) * 1536 + kclog*8, Kn + (w*8)*64);
            gll16(vgbase + (size_t)(w*16 + vsrow) * SS + kb + vclog*8,  Vn + (w*16)*32);
        }
        if (jt < mynkt) {
            KVfrags f;
            f.k00 = *(const bf16x8*)(Kb + l15*64 + swkA);
            f.k01 = *(const bf16x8*)(Kb + l15*64 + swkB);
            f.k10 = *(const bf16x8*)(Kb + (16+l15)*64 + swkA);
            f.k11 = *(const bf16x8*)(Kb + (16+l15)*64 + swkB);
            f.v0  = *(const bf16x8*)(Vb + l15*32 + swv);
            f.v1  = *(const bf16x8*)(Vb + (16+l15)*32 + swv);
            f.v2  = *(const bf16x8*)(Vb + (32+l15)*32 + swv);
            f.v3  = *(const bf16x8*)(Vb + (48+l15)*32 + swv);
            attn_step(st, f, qf0, qf1, jt * 32, qrow0, lane);
        }
        __syncthreads();
    }

    // epilogue: O^T regs -> LDS (aliases staging; all compute done) -> stores
    float* otw = (float*)smem + w * 16 * 68;    // 4*16*68*4 = 17408 B total
    float inv = 1.f / st.l;
    #pragma unroll
    for (int r = 0; r < 4; ++r) {
        otw[l15*68 +  0 + quad*4 + r] = st.o0[r] * inv;
        otw[l15*68 + 16 + quad*4 + r] = st.o1[r] * inv;
        otw[l15*68 + 32 + quad*4 + r] = st.o2[r] * inv;
        otw[l15*68 + 48 + quad*4 + r] = st.o3[r] * inv;
    }
    asm volatile("s_waitcnt lgkmcnt(0)" ::: "memory");
    int row = lane >> 2, ch = (lane & 3) * 16;
    union { __bf16 hh[16]; uint4 q4[2]; } ob;
    #pragma unroll
    for (int t2 = 0; t2 < 16; ++t2) ob.hh[t2] = f2b(otw[row*68 + ch + t2]);
    __bf16* cp = ctx + (size_t)(b*SS + qrow0 + row) * 512 + h*64 + ch;
    *(uint4*)cp = ob.q4[0];
    *(uint4*)(cp + 8) = ob.q4[1];
}

// ================= final projection =================
__global__ __launch_bounds__(256) void proj_kernel(
    const float* __restrict__ h, const float* __restrict__ Wp,
    const float* __restrict__ bp, float* __restrict__ out)
{
    int rid = blockIdx.x * 8 + (threadIdx.x >> 5);
    int col = threadIdx.x & 31;
    int b = rid / TT, i = rid - b * TT;
    const float* x = h + ((size_t)(b*SS) + 3*i + 1) * HDIM;
    float acc = bp[col];
    for (int kk = 0; kk < HDIM; ++kk)
        acc += x[kk] * Wp[kk * ADIM + col];
    out[(size_t)rid * ADIM + col] = acc;
}

extern "C" void kernel_launch(void* const* d_in, const int* in_sizes, int n_in,
                              void* d_out, int out_size, void* d_ws, size_t ws_size,
                              hipStream_t stream)
{
    (void)in_sizes; (void)n_in; (void)out_size; (void)ws_size;
    const int*   timesteps = (const int*)  d_in[0];
    const float* state0    = (const float*)d_in[1];
    const float* state1    = (const float*)d_in[2];
    const float* actions   = (const float*)d_in[3];
    const float* time_emb  = (const float*)d_in[4];
    const float* Ws  = (const float*)d_in[5];
    const float* bs  = (const float*)d_in[6];
    const float* Wa  = (const float*)d_in[7];
    const float* ba  = (const float*)d_in[8];
    const float* Wq  = (const float*)d_in[9];
    const float* bq  = (const float*)d_in[10];
    const float* Wk  = (const float*)d_in[11];
    const float* bk  = (const float*)d_in[12];
    const float* Wv  = (const float*)d_in[13];
    const float* bv  = (const float*)d_in[14];
    const float* Wo  = (const float*)d_in[15];
    const float* bo  = (const float*)d_in[16];
    const float* W1  = (const float*)d_in[17];
    const float* b1  = (const float*)d_in[18];
    const float* W2  = (const float*)d_in[19];
    const float* b2  = (const float*)d_in[20];
    const float* ln1g = (const float*)d_in[21];
    const float* ln1b = (const float*)d_in[22];
    const float* ln2g = (const float*)d_in[23];
    const float* ln2b = (const float*)d_in[24];
    const float* elng = (const float*)d_in[25];
    const float* elnb = (const float*)d_in[26];
    const float* Wp   = (const float*)d_in[27];
    const float* bp   = (const float*)d_in[28];
    float* out = (float*)d_out;

    const size_t SZ = (size_t)MS * HDIM;          // 3,145,728
    char* p = (char*)d_ws;
    float*  h    = (float*)p;            p += SZ * 4;
    float*  tmp  = (float*)p;            p += SZ * 4;
    __bf16* h_bf = (__bf16*)p;           p += SZ * 2;
    __bf16* qkv  = (__bf16*)p;           p += SZ * 3 * 2;
    __bf16* ctx  = (__bf16*)p;           p += SZ * 2;
    __bf16* VT   = (__bf16*)p;           p += SZ * 2;
    __bf16* wqkvT = (__bf16*)p;          p += (size_t)1536 * 512 * 2;
    __bf16* woT   = (__bf16*)p;          p += (size_t)512 * 512 * 2;
    __bf16* w1T   = (__bf16*)p;          p += (size_t)2048 * 512 * 2;
    __bf16* w2T   = (__bf16*)p;          p += (size_t)512 * 2048 * 2;
    float*  biasq = (float*)p;           p += 1536 * 4;
    __bf16* hid   = qkv;                 // MS x DFF bf16, aliases qkv+ctx
    __bf16* tmp_bf = (__bf16*)tmp;       // bf16 view of tmp region

    embed_ln_kernel<<<MS, 512, 0, stream>>>(timesteps, state0, state1, actions, time_emb,
                                            Ws, bs, Wa, ba, elng, elnb, h, h_bf);

    dim3 gQKV(1536/128, MS/128);   // 12 x 48
    dim3 gO  (512/128,  MS/64);    // 4 x 96  (64-row tiles)
    dim3 gF1 (2048/128, MS/128);   // 16 x 48
    dim3 gV  (NH, MS/64);          // 8 x 96

    for (int lyr = 0; lyr < NBLK; ++lyr) {
        const float* wq = Wq + (size_t)lyr * HDIM * HDIM;
        const float* wk = Wk + (size_t)lyr * HDIM * HDIM;
        const float* wv = Wv + (size_t)lyr * HDIM * HDIM;
        const float* wo = Wo + (size_t)lyr * HDIM * HDIM;
        const float* w1 = W1 + (size_t)lyr * HDIM * DFF;
        const float* w2 = W2 + (size_t)lyr * DFF * HDIM;

        pack_kernel<<<769, 256, 0, stream>>>(wq, wk, wv, wo, w1, w2,
                                             bq + lyr*HDIM, bk + lyr*HDIM, bv + lyr*HDIM,
                                             wqkvT, woT, w1T, w2T, biasq);
        gemm_mfma<128><<<gQKV, 256, 0, stream>>>(h_bf, wqkvT, biasq, qkv, MS, 1536, HDIM, 1);
        vtrans_kernel<<<gV, 256, 0, stream>>>(qkv, VT);
        attn_kernel<<<dim3(768), 256, 0, stream>>>(qkv, VT, ctx);
        gemm_mfma<64><<<gO, 256, 0, stream>>>(ctx, woT, bo + lyr*HDIM, tmp_bf, MS, HDIM, HDIM, 1);
        ln_add_kernel<<<MS, 512, 0, stream>>>(h, tmp_bf, ln1g + lyr*HDIM, ln1b + lyr*HDIM, h_bf);
        gemm_mfma<128><<<gF1, 256, 0, stream>>>(h_bf, w1T, b1 + lyr*DFF, hid, MS, DFF, HDIM, 1 | 2);
        gemm_mfma<64><<<gO, 256, 0, stream>>>(hid, w2T, b2 + lyr*HDIM, tmp_bf, MS, HDIM, DFF, 1);
        ln_add_kernel<<<MS, 512, 0, stream>>>(h, tmp_bf, ln2g + lyr*HDIM, ln2b + lyr*HDIM, h_bf);
    }

    proj_kernel<<<(BB*TT)/8, 256, 0, stream>>>(h, Wp, bp, out);
}

// Round 8
// 1226.457 us; speedup vs baseline: 1.3571x; 1.0340x over previous
//
#include <hip/hip_runtime.h>
#include <hip/hip_bf16.h>
#include <math.h>

#define BB 4
#define TT 512
#define SDIM 64
#define ADIM 32
#define HDIM 512
#define NH 8
#define NBLK 6
#define DFF 2048
#define SS 1536          // 3*T
#define DH 64
#define MS (BB*SS)       // 6144 rows

typedef __attribute__((ext_vector_type(8))) __bf16 bf16x8;
typedef __attribute__((ext_vector_type(4))) float f32x4;

__device__ __forceinline__ __bf16 f2b(float x) { return (__bf16)x; }

// async global->LDS, 16 B per lane; LDS dest = wave-uniform base + lane*16
__device__ __forceinline__ void gll16(const void* g, void* l) {
    __builtin_amdgcn_global_load_lds(
        (const __attribute__((address_space(1))) unsigned int*)g,
        (__attribute__((address_space(3))) unsigned int*)l, 16, 0, 0);
}

// ================= shuffle-based LN over 512 threads =================
__device__ __forceinline__ float block_ln2(float val, int tid,
                                           const float* __restrict__ g,
                                           const float* __restrict__ bvec,
                                           float* red)
{
    float s = val, sq = val * val;
    #pragma unroll
    for (int off = 32; off; off >>= 1) { s += __shfl_xor(s, off); sq += __shfl_xor(sq, off); }
    int w = tid >> 6;
    if ((tid & 63) == 0) { red[w] = s; red[8 + w] = sq; }
    __syncthreads();
    float S = 0.f, SQ = 0.f;
    #pragma unroll
    for (int i = 0; i < 8; ++i) { S += red[i]; SQ += red[8 + i]; }
    float mean = S * (1.f / HDIM);
    float var  = SQ * (1.f / HDIM) - mean * mean;
    return (val - mean) * rsqrtf(var + 1e-5f) * g[tid] + bvec[tid];
}

// ================= embed + LN -> h (fp32) and h_bf (bf16) =================
__global__ __launch_bounds__(512) void embed_ln_kernel(
    const int* __restrict__ timesteps,
    const float* __restrict__ state0, const float* __restrict__ state1,
    const float* __restrict__ actions, const float* __restrict__ time_emb,
    const float* __restrict__ Ws, const float* __restrict__ bs,
    const float* __restrict__ Wa, const float* __restrict__ ba,
    const float* __restrict__ eg, const float* __restrict__ eb,
    float* __restrict__ h, __bf16* __restrict__ h_bf)
{
    __shared__ float xs[SDIM];
    __shared__ float red[16];
    int row = blockIdx.x;
    int b = row / SS;
    int pos = row - b * SS;
    int i = pos / 3;
    int t = pos - i * 3;
    int col = threadIdx.x;

    const float* x; const float* W; const float* bias; int K;
    if (t == 0)      { x = state0  + (size_t)(b*TT + i) * SDIM; W = Ws; bias = bs; K = SDIM; }
    else if (t == 1) { x = state1  + (size_t)(b*TT + i) * SDIM; W = Ws; bias = bs; K = SDIM; }
    else             { x = actions + (size_t)(b*TT + i) * ADIM; W = Wa; bias = ba; K = ADIM; }

    if (col < K) xs[col] = x[col];
    __syncthreads();

    int ts = timesteps[b*TT + i];
    float acc = bias[col] + time_emb[(size_t)ts * HDIM + col];
    for (int kk = 0; kk < K; ++kk)
        acc += xs[kk] * W[(size_t)kk * HDIM + col];

    float y = block_ln2(acc, col, eg, eb, red);
    h[(size_t)row * HDIM + col] = y;
    h_bf[(size_t)row * HDIM + col] = f2b(y);
}

// ================= residual add + LN (y in bf16) =================
__global__ __launch_bounds__(512) void ln_add_kernel(
    float* __restrict__ h, const __bf16* __restrict__ y,
    const float* __restrict__ g, const float* __restrict__ bvec,
    __bf16* __restrict__ h_bf)
{
    __shared__ float red[16];
    int row = blockIdx.x, col = threadIdx.x;
    float val = h[(size_t)row * HDIM + col] + (float)y[(size_t)row * HDIM + col];
    float o = block_ln2(val, col, g, bvec, red);
    h[(size_t)row * HDIM + col] = o;
    h_bf[(size_t)row * HDIM + col] = f2b(o);
}

// ================= weight pack: fp32 [K][N] -> bf16 [N][K] =================
__global__ __launch_bounds__(256) void pack_kernel(
    const float* __restrict__ wq, const float* __restrict__ wk,
    const float* __restrict__ wv, const float* __restrict__ wo,
    const float* __restrict__ w1, const float* __restrict__ w2,
    const float* __restrict__ bq_, const float* __restrict__ bk_, const float* __restrict__ bv_,
    __bf16* __restrict__ wqkvT, __bf16* __restrict__ woT,
    __bf16* __restrict__ w1T, __bf16* __restrict__ w2T, float* __restrict__ biasq)
{
    int bid = blockIdx.x;
    int tid = threadIdx.x;
    if (bid == 768) {
        for (int i = tid; i < 1536; i += 256)
            biasq[i] = (i < 512) ? bq_[i] : ((i < 1024) ? bk_[i-512] : bv_[i-1024]);
        return;
    }
    __shared__ float Ls[64][65];
    const float* src; __bf16* dst; int K, N, kt, nt;
    if (bid < 192) {
        int sec = bid / 64, t = bid % 64;
        src = (sec == 0) ? wq : (sec == 1) ? wk : wv;
        dst = wqkvT + (size_t)sec * 512 * 512;
        K = 512; N = 512; nt = t >> 3; kt = t & 7;
    } else if (bid < 256) {
        int t = bid - 192; src = wo; dst = woT; K = 512; N = 512; nt = t >> 3; kt = t & 7;
    } else if (bid < 512) {
        int t = bid - 256; src = w1; dst = w1T; K = 512; N = 2048; nt = t >> 3; kt = t & 7;
    } else {
        int t = bid - 512; src = w2; dst = w2T; K = 2048; N = 512; nt = t & 7; kt = t >> 3;
    }
    int k0 = kt * 64, n0 = nt * 64;
    int rr = tid >> 4, cc = (tid & 15) * 4;
    #pragma unroll
    for (int p = 0; p < 4; ++p) {
        float4 v = *(const float4*)(src + (size_t)(k0 + rr + p*16) * N + n0 + cc);
        Ls[rr + p*16][cc] = v.x; Ls[rr + p*16][cc+1] = v.y;
        Ls[rr + p*16][cc+2] = v.z; Ls[rr + p*16][cc+3] = v.w;
    }
    __syncthreads();
    int nn = tid >> 3, kc = (tid & 7) * 8;
    #pragma unroll
    for (int p = 0; p < 2; ++p) {
        __bf16 t8[8];
        #pragma unroll
        for (int t2 = 0; t2 < 8; ++t2) t8[t2] = f2b(Ls[kc + t2][nn + p*32]);
        *(uint4*)(dst + (size_t)(n0 + nn + p*32) * K + k0 + kc) = *(uint4*)t8;
    }
}

// ================= V transpose: qkv v-section -> VT[(b*NH+h)*64+d][s] =================
__global__ __launch_bounds__(256) void vtrans_kernel(
    const __bf16* __restrict__ qkv, __bf16* __restrict__ VT)
{
    __shared__ __bf16 Ls[64][72];
    int dt = blockIdx.x;          // 0..7 (head)
    int st = blockIdx.y;          // 0..95
    int s0 = st * 64;
    int b  = s0 / SS;
    int srel = s0 - b * SS;
    int tid = threadIdx.x;
    int r = tid >> 3, ch = tid & 7;
    #pragma unroll
    for (int p = 0; p < 2; ++p) {
        uint4 v = *(const uint4*)(qkv + (size_t)(s0 + r + p*32) * 1536 + 1024 + dt*64 + ch*8);
        *(uint4*)&Ls[r + p*32][ch*8] = v;
    }
    __syncthreads();
    int dd = tid >> 3;
    #pragma unroll
    for (int p = 0; p < 2; ++p) {
        __bf16 t8[8];
        #pragma unroll
        for (int t2 = 0; t2 < 8; ++t2) t8[t2] = Ls[ch*8 + t2][dd + p*32];
        *(uint4*)(VT + ((size_t)(b*NH + dt) * 64 + dd + p*32) * SS + srel + ch*8) = *(uint4*)t8;
    }
}

// ================= bf16 MFMA GEMM, double-buffered async LDS staging =================
// K-loop shape: barrier (drains prev iter's prefetch) -> issue prefetch buf^1
// -> ds_read+MFMA on buf. One barrier per iter; load latency overlaps compute.
template<int MT>
__global__ __launch_bounds__(256) void gemm_mfma(
    const __bf16* __restrict__ A, const __bf16* __restrict__ Bt,
    const float* __restrict__ bias, void* __restrict__ Cout,
    int M, int N, int K, int flags)
{
    constexpr int MI = MT / 32;
    __shared__ __bf16 As[2][MT][32];
    __shared__ __bf16 Bs[2][128][32];
    int tid = threadIdx.x;
    int wave = tid >> 6, lane = tid & 63;
    int l15 = lane & 15, quad = lane >> 4;
    int wy = wave >> 1, wx = wave & 1;
    int m0 = blockIdx.y * MT, n0 = blockIdx.x * 128;

    int srow = lane >> 2;
    int clog = (lane & 3) ^ ((lane >> 3) & 3);
    int pchunk = (quad ^ ((l15 >> 1) & 3)) * 8;

    f32x4 acc[MI][4];
    #pragma unroll
    for (int i = 0; i < MI; ++i)
        #pragma unroll
        for (int j = 0; j < 4; ++j) acc[i][j] = (f32x4){0.f,0.f,0.f,0.f};

    const __bf16* Abase = A  + (size_t)m0 * K + clog * 8;
    const __bf16* Bbase = Bt + (size_t)n0 * K + clog * 8;
    int NK = K >> 5;

    // prologue: stage k-tile 0 into buffer 0
    #pragma unroll
    for (int q = 0; q < MT/64; ++q) {
        int r0 = (wave * (MT/64) + q) * 16;
        gll16(Abase + (size_t)(r0 + srow) * K, &As[0][r0][0]);
    }
    #pragma unroll
    for (int q = 0; q < 2; ++q) {
        int r0 = (wave * 2 + q) * 16;
        gll16(Bbase + (size_t)(r0 + srow) * K, &Bs[0][r0][0]);
    }

    for (int kt = 0; kt < NK; ++kt) {
        int buf = kt & 1;
        __syncthreads();   // drains the loads for `buf` (issued one full iter ago)
        if (kt + 1 < NK) {
            int k0 = (kt + 1) << 5;
            #pragma unroll
            for (int q = 0; q < MT/64; ++q) {
                int r0 = (wave * (MT/64) + q) * 16;
                gll16(Abase + (size_t)(r0 + srow) * K + k0, &As[buf^1][r0][0]);
            }
            #pragma unroll
            for (int q = 0; q < 2; ++q) {
                int r0 = (wave * 2 + q) * 16;
                gll16(Bbase + (size_t)(r0 + srow) * K + k0, &Bs[buf^1][r0][0]);
            }
        }
        bf16x8 af[MI], bf[4];
        #pragma unroll
        for (int i = 0; i < MI; ++i) af[i] = *(const bf16x8*)&As[buf][wy*(MT/2) + i*16 + l15][pchunk];
        #pragma unroll
        for (int j = 0; j < 4; ++j)  bf[j] = *(const bf16x8*)&Bs[buf][wx*64 + j*16 + l15][pchunk];
        #pragma unroll
        for (int i = 0; i < MI; ++i)
            #pragma unroll
            for (int j = 0; j < 4; ++j)
                acc[i][j] = __builtin_amdgcn_mfma_f32_16x16x32_bf16(af[i], bf[j], acc[i][j], 0, 0, 0);
    }

    float* Cf = (float*)Cout;
    __bf16* Cb = (__bf16*)Cout;
    int obf = flags & 1, gel = flags & 2;
    #pragma unroll
    for (int j = 0; j < 4; ++j) {
        int cc = n0 + wx*64 + j*16 + l15;
        float bv = bias[cc];
        #pragma unroll
        for (int i = 0; i < MI; ++i) {
            #pragma unroll
            for (int r = 0; r < 4; ++r) {
                int rr = m0 + wy*(MT/2) + i*16 + quad*4 + r;
                float v = acc[i][j][r] + bv;
                if (gel) v = 0.5f * v * (1.f + erff(v * 0.70710678118654752f));
                if (obf) Cb[(size_t)rr * N + cc] = f2b(v);
                else     Cf[(size_t)rr * N + cc] = v;
            }
        }
    }
}

// ================= S^T-layout MFMA flash attention, LDS-shared K/V =================
#define SM_C 0.18033688011112042f   // (1/8) * log2(e)

struct KVfrags { bf16x8 k00, k01, k10, k11, v0, v1, v2, v3; };

__device__ __forceinline__ unsigned pack2bf(float a, float b)
{
    union { __bf16 h[2]; unsigned u; } t;
    t.h[0] = (__bf16)a; t.h[1] = (__bf16)b;
    return t.u;
}

struct AttnState {
    f32x4 o0, o1, o2, o3;
    float m, l;
};

__device__ __forceinline__ void attn_step(AttnState& st, const KVfrags& kv,
                                          bf16x8 qf0, bf16x8 qf1,
                                          int kb, int qrow0, int lane)
{
    int l15 = lane & 15, quad = lane >> 4;
    f32x4 s0 = {0.f,0.f,0.f,0.f}, s1 = {0.f,0.f,0.f,0.f};
    s0 = __builtin_amdgcn_mfma_f32_16x16x32_bf16(kv.k00, qf0, s0, 0, 0, 0);
    s0 = __builtin_amdgcn_mfma_f32_16x16x32_bf16(kv.k01, qf1, s0, 0, 0, 0);
    s1 = __builtin_amdgcn_mfma_f32_16x16x32_bf16(kv.k10, qf0, s1, 0, 0, 0);
    s1 = __builtin_amdgcn_mfma_f32_16x16x32_bf16(kv.k11, qf1, s1, 0, 0, 0);

    if (kb + 31 > qrow0) {          // wave-uniform: tile straddles diagonal
        int qrow = qrow0 + l15;
        #pragma unroll
        for (int r = 0; r < 4; ++r) {
            int c0 = kb + quad*4 + r;
            if (c0 > qrow)      s0[r] = -1e30f;
            if (c0 + 16 > qrow) s1[r] = -1e30f;
        }
    }

    float tm = fmaxf(fmaxf(fmaxf(s0[0], s0[1]), fmaxf(s0[2], s0[3])),
                     fmaxf(fmaxf(s1[0], s1[1]), fmaxf(s1[2], s1[3])));
    tm = fmaxf(tm, __shfl_xor(tm, 16));
    tm = fmaxf(tm, __shfl_xor(tm, 32));
    float mnew = fmaxf(st.m, tm);
    float alpha = __builtin_amdgcn_exp2f((st.m - mnew) * SM_C);

    float p0[4], p1[4], rs = 0.f;
    #pragma unroll
    for (int r = 0; r < 4; ++r) {
        p0[r] = __builtin_amdgcn_exp2f((s0[r] - mnew) * SM_C);
        p1[r] = __builtin_amdgcn_exp2f((s1[r] - mnew) * SM_C);
        rs += p0[r] + p1[r];
    }
    rs += __shfl_xor(rs, 16);
    rs += __shfl_xor(rs, 32);
    st.l = st.l * alpha + rs;
    st.m = mnew;
    st.o0 *= alpha; st.o1 *= alpha; st.o2 *= alpha; st.o3 *= alpha;

    // P^T -> PV B-frag; all shuffles at full wave exec, per-lane cndmask after.
    unsigned pk0a = pack2bf(p0[0], p0[1]), pk0b = pack2bf(p0[2], p0[3]);
    unsigned pk1a = pack2bf(p1[0], p1[1]), pk1b = pack2bf(p1[2], p1[3]);
    int sA = l15 + (quad & 1) * 32;
    int sB = sA + 16;
    int hi = quad >> 1;
    unsigned a0A = (unsigned)__shfl((int)pk0a, sA);
    unsigned a1A = (unsigned)__shfl((int)pk1a, sA);
    unsigned b0A = (unsigned)__shfl((int)pk0b, sA);
    unsigned b1A = (unsigned)__shfl((int)pk1b, sA);
    unsigned a0B = (unsigned)__shfl((int)pk0a, sB);
    unsigned a1B = (unsigned)__shfl((int)pk1a, sB);
    unsigned b0B = (unsigned)__shfl((int)pk0b, sB);
    unsigned b1B = (unsigned)__shfl((int)pk1b, sB);
    union { unsigned u[4]; bf16x8 v; } pb;
    pb.u[0] = hi ? a1A : a0A;
    pb.u[1] = hi ? b1A : b0A;
    pb.u[2] = hi ? a1B : a0B;
    pb.u[3] = hi ? b1B : b0B;

    st.o0 = __builtin_amdgcn_mfma_f32_16x16x32_bf16(kv.v0, pb.v, st.o0, 0, 0, 0);
    st.o1 = __builtin_amdgcn_mfma_f32_16x16x32_bf16(kv.v1, pb.v, st.o1, 0, 0, 0);
    st.o2 = __builtin_amdgcn_mfma_f32_16x16x32_bf16(kv.v2, pb.v, st.o2, 0, 0, 0);
    st.o3 = __builtin_amdgcn_mfma_f32_16x16x32_bf16(kv.v3, pb.v, st.o3, 0, 0, 0);
}

// grid: 768 blocks (region-interleaved qt), 256 threads; block shares K/V via LDS.
// LDS (24 KB, double-buffered): K tile [32 s][64 d] (8 KB/buf) chunk-swizzled
// p = c ^ (row&7); V^T tile [64 d][32 s] (4 KB/buf) p = c ^ ((row>>1)&3).
__global__ __launch_bounds__(256, 3) void attn_kernel(
    const __bf16* __restrict__ qkv, const __bf16* __restrict__ VT,
    __bf16* __restrict__ ctx)
{
    __shared__ __align__(16) char smem[24576];

    int x = blockIdx.x;
    int region = x >> 8;          // 0,1,2
    int j = x & 255;
    int i = j >> 5;               // 0..7
    int hb = j & 31;
    int qt = (region == 0) ? i : (region == 1) ? (15 - i) : (16 + i);
    int h = hb >> 2, b = hb & 3;

    int tid = threadIdx.x;
    int w = tid >> 6, lane = tid & 63;
    int l15 = lane & 15, quad = lane >> 4;
    int qrow0 = qt * 64 + w * 16;

    const __bf16* qp = qkv + (size_t)(b*SS + qrow0 + l15) * 1536 + h*64 + quad*8;
    bf16x8 qf0 = *(const bf16x8*)qp;
    bf16x8 qf1 = *(const bf16x8*)(qp + 32);

    // staging bases
    const __bf16* kgbase = qkv + (size_t)(b*SS) * 1536 + 512 + h*64;     // + row*1536
    const __bf16* vgbase = VT + (size_t)(b*NH + h) * 64 * SS;            // + row*SS
    int ksrow = lane >> 3;                       // 0..7
    int kclog = (lane & 7) ^ ((lane >> 3) & 7);
    int vsrow = lane >> 2;                       // 0..15
    int vclog = (lane & 3) ^ ((lane >> 3) & 3);

    // frag-read swizzled chunk offsets
    int swkA = (quad ^ (l15 & 7)) * 8;
    int swkB = ((quad + 4) ^ (l15 & 7)) * 8;
    int swv  = (quad ^ ((l15 >> 1) & 3)) * 8;

    AttnState st;
    st.o0 = (f32x4){0.f,0.f,0.f,0.f}; st.o1 = st.o0; st.o2 = st.o0; st.o3 = st.o0;
    st.m = -1e30f; st.l = 0.f;

    int mynkt = (qrow0 + 47) >> 5;
    int nkt_max = 2*qt + 2;

    // stage tile 0 into buffer 0
    gll16(kgbase + (size_t)(w*8 + ksrow) * 1536 + kclog*8, (__bf16*)smem + (w*8)*64);
    gll16(vgbase + (size_t)(w*16 + vsrow) * SS + vclog*8,  (__bf16*)(smem + 16384) + (w*16)*32);
    __syncthreads();

    for (int jt = 0; jt < nkt_max; ++jt) {
        int buf = jt & 1;
        __bf16* Kb = (__bf16*)(smem + buf * 8192);
        __bf16* Vb = (__bf16*)(smem + 16384 + buf * 4096);
        __bf16* Kn = (__bf16*)(smem + (buf ^ 1) * 8192);
        __bf16* Vn = (__bf16*)(smem + 16384 + (buf ^ 1) * 4096);
        if (jt + 1 < nkt_max) {
            int kb = (jt + 1) * 32;
            gll16(kgbase + (size_t)(kb + w*8 + ksrow) * 1536 + kclog*8, Kn + (w*8)*64);
            gll16(vgbase + (size_t)(w*16 + vsrow) * SS + kb + vclog*8,  Vn + (w*16)*32);
        }
        if (jt < mynkt) {
            KVfrags f;
            f.k00 = *(const bf16x8*)(Kb + l15*64 + swkA);
            f.k01 = *(const bf16x8*)(Kb + l15*64 + swkB);
            f.k10 = *(const bf16x8*)(Kb + (16+l15)*64 + swkA);
            f.k11 = *(const bf16x8*)(Kb + (16+l15)*64 + swkB);
            f.v0  = *(const bf16x8*)(Vb + l15*32 + swv);
            f.v1  = *(const bf16x8*)(Vb + (16+l15)*32 + swv);
            f.v2  = *(const bf16x8*)(Vb + (32+l15)*32 + swv);
            f.v3  = *(const bf16x8*)(Vb + (48+l15)*32 + swv);
            attn_step(st, f, qf0, qf1, jt * 32, qrow0, lane);
        }
        __syncthreads();
    }

    // epilogue: O^T regs -> LDS (aliases staging; all compute done) -> stores
    float* otw = (float*)smem + w * 16 * 68;    // 4*16*68*4 = 17408 B total
    float inv = 1.f / st.l;
    #pragma unroll
    for (int r = 0; r < 4; ++r) {
        otw[l15*68 +  0 + quad*4 + r] = st.o0[r] * inv;
        otw[l15*68 + 16 + quad*4 + r] = st.o1[r] * inv;
        otw[l15*68 + 32 + quad*4 + r] = st.o2[r] * inv;
        otw[l15*68 + 48 + quad*4 + r] = st.o3[r] * inv;
    }
    asm volatile("s_waitcnt lgkmcnt(0)" ::: "memory");
    int row = lane >> 2, ch = (lane & 3) * 16;
    union { __bf16 hh[16]; uint4 q4[2]; } ob;
    #pragma unroll
    for (int t2 = 0; t2 < 16; ++t2) ob.hh[t2] = f2b(otw[row*68 + ch + t2]);
    __bf16* cp = ctx + (size_t)(b*SS + qrow0 + row) * 512 + h*64 + ch;
    *(uint4*)cp = ob.q4[0];
    *(uint4*)(cp + 8) = ob.q4[1];
}

// ================= final projection =================
__global__ __launch_bounds__(256) void proj_kernel(
    const float* __restrict__ h, const float* __restrict__ Wp,
    const float* __restrict__ bp, float* __restrict__ out)
{
    int rid = blockIdx.x * 8 + (threadIdx.x >> 5);
    int col = threadIdx.x & 31;
    int b = rid / TT, i = rid - b * TT;
    const float* x = h + ((size_t)(b*SS) + 3*i + 1) * HDIM;
    float acc = bp[col];
    for (int kk = 0; kk < HDIM; ++kk)
        acc += x[kk] * Wp[kk * ADIM + col];
    out[(size_t)rid * ADIM + col] = acc;
}

extern "C" void kernel_launch(void* const* d_in, const int* in_sizes, int n_in,
                              void* d_out, int out_size, void* d_ws, size_t ws_size,
                              hipStream_t stream)
{
    (void)in_sizes; (void)n_in; (void)out_size; (void)ws_size;
    const int*   timesteps = (const int*)  d_in[0];
    const float* state0    = (const float*)d_in[1];
    const float* state1    = (const float*)d_in[2];
    const float* actions   = (const float*)d_in[3];
    const float* time_emb  = (const float*)d_in[4];
    const float* Ws  = (const float*)d_in[5];
    const float* bs  = (const float*)d_in[6];
    const float* Wa  = (const float*)d_in[7];
    const float* ba  = (const float*)d_in[8];
    const float* Wq  = (const float*)d_in[9];
    const float* bq  = (const float*)d_in[10];
    const float* Wk  = (const float*)d_in[11];
    const float* bk  = (const float*)d_in[12];
    const float* Wv  = (const float*)d_in[13];
    const float* bv  = (const float*)d_in[14];
    const float* Wo  = (const float*)d_in[15];
    const float* bo  = (const float*)d_in[16];
    const float* W1  = (const float*)d_in[17];
    const float* b1  = (const float*)d_in[18];
    const float* W2  = (const float*)d_in[19];
    const float* b2  = (const float*)d_in[20];
    const float* ln1g = (const float*)d_in[21];
    const float* ln1b = (const float*)d_in[22];
    const float* ln2g = (const float*)d_in[23];
    const float* ln2b = (const float*)d_in[24];
    const float* elng = (const float*)d_in[25];
    const float* elnb = (const float*)d_in[26];
    const float* Wp   = (const float*)d_in[27];
    const float* bp   = (const float*)d_in[28];
    float* out = (float*)d_out;

    const size_t SZ = (size_t)MS * HDIM;          // 3,145,728
    char* p = (char*)d_ws;
    float*  h    = (float*)p;            p += SZ * 4;
    float*  tmp  = (float*)p;            p += SZ * 4;
    __bf16* h_bf = (__bf16*)p;           p += SZ * 2;
    __bf16* qkv  = (__bf16*)p;           p += SZ * 3 * 2;
    __bf16* ctx  = (__bf16*)p;           p += SZ * 2;
    __bf16* VT   = (__bf16*)p;           p += SZ * 2;
    __bf16* wqkvT = (__bf16*)p;          p += (size_t)1536 * 512 * 2;
    __bf16* woT   = (__bf16*)p;          p += (size_t)512 * 512 * 2;
    __bf16* w1T   = (__bf16*)p;          p += (size_t)2048 * 512 * 2;
    __bf16* w2T   = (__bf16*)p;          p += (size_t)512 * 2048 * 2;
    float*  biasq = (float*)p;           p += 1536 * 4;
    __bf16* hid   = qkv;                 // MS x DFF bf16, aliases qkv+ctx
    __bf16* tmp_bf = (__bf16*)tmp;       // bf16 view of tmp region

    embed_ln_kernel<<<MS, 512, 0, stream>>>(timesteps, state0, state1, actions, time_emb,
                                            Ws, bs, Wa, ba, elng, elnb, h, h_bf);

    dim3 gQKV(1536/128, MS/128);   // 12 x 48
    dim3 gO  (512/128,  MS/64);    // 4 x 96  (64-row tiles)
    dim3 gF1 (2048/128, MS/128);   // 16 x 48
    dim3 gV  (NH, MS/64);          // 8 x 96

    for (int lyr = 0; lyr < NBLK; ++lyr) {
        const float* wq = Wq + (size_t)lyr * HDIM * HDIM;
        const float* wk = Wk + (size_t)lyr * HDIM * HDIM;
        const float* wv = Wv + (size_t)lyr * HDIM * HDIM;
        const float* wo = Wo + (size_t)lyr * HDIM * HDIM;
        const float* w1 = W1 + (size_t)lyr * HDIM * DFF;
        const float* w2 = W2 + (size_t)lyr * DFF * HDIM;

        pack_kernel<<<769, 256, 0, stream>>>(wq, wk, wv, wo, w1, w2,
                                             bq + lyr*HDIM, bk + lyr*HDIM, bv + lyr*HDIM,
                                             wqkvT, woT, w1T, w2T, biasq);
        gemm_mfma<128><<<gQKV, 256, 0, stream>>>(h_bf, wqkvT, biasq, qkv, MS, 1536, HDIM, 1);
        vtrans_kernel<<<gV, 256, 0, stream>>>(qkv, VT);
        attn_kernel<<<dim3(768), 256, 0, stream>>>(qkv, VT, ctx);
        gemm_mfma<64><<<gO, 256, 0, stream>>>(ctx, woT, bo + lyr*HDIM, tmp_bf, MS, HDIM, HDIM, 1);
        ln_add_kernel<<<MS, 512, 0, stream>>>(h, tmp_bf, ln1g + lyr*HDIM, ln1b + lyr*HDIM, h_bf);
        gemm_mfma<128><<<gF1, 256, 0, stream>>>(h_bf, w1T, b1 + lyr*DFF, hid, MS, DFF, HDIM, 1 | 2);
        gemm_mfma<64><<<gO, 256, 0, stream>>>(hid, w2T, b2 + lyr*HDIM, tmp_bf, MS, HDIM, DFF, 1);
        ln_add_kernel<<<MS, 512, 0, stream>>>(h, tmp_bf, ln2g + lyr*HDIM, ln2b + lyr*HDIM, h_bf);
    }

    proj_kernel<<<(BB*TT)/8, 256, 0, stream>>>(h, Wp, bp, out);
}

// Round 9
// 1197.536 us; speedup vs baseline: 1.3898x; 1.0242x over previous
//
#include <hip/hip_runtime.h>
#include <hip/hip_bf16.h>
#include <math.h>

#define BB 4
#define TT 512
#define SDIM 64
#define ADIM 32
#define HDIM 512
#define NH 8
#define NBLK 6
#define DFF 2048
#define SS 1536          // 3*T
#define DH 64
#define MS (BB*SS)       // 6144 rows

typedef __attribute__((ext_vector_type(8))) __bf16 bf16x8;
typedef __attribute__((ext_vector_type(4))) float f32x4;

__device__ __forceinline__ __bf16 f2b(float x) { return (__bf16)x; }

// async global->LDS, 16 B per lane; LDS dest = wave-uniform base + lane*16
__device__ __forceinline__ void gll16(const void* g, void* l) {
    __builtin_amdgcn_global_load_lds(
        (const __attribute__((address_space(1))) unsigned int*)g,
        (__attribute__((address_space(3))) unsigned int*)l, 16, 0, 0);
}

// ================= shuffle-based LN over 512 threads =================
__device__ __forceinline__ float block_ln2(float val, int tid,
                                           const float* __restrict__ g,
                                           const float* __restrict__ bvec,
                                           float* red)
{
    float s = val, sq = val * val;
    #pragma unroll
    for (int off = 32; off; off >>= 1) { s += __shfl_xor(s, off); sq += __shfl_xor(sq, off); }
    int w = tid >> 6;
    if ((tid & 63) == 0) { red[w] = s; red[8 + w] = sq; }
    __syncthreads();
    float S = 0.f, SQ = 0.f;
    #pragma unroll
    for (int i = 0; i < 8; ++i) { S += red[i]; SQ += red[8 + i]; }
    float mean = S * (1.f / HDIM);
    float var  = SQ * (1.f / HDIM) - mean * mean;
    return (val - mean) * rsqrtf(var + 1e-5f) * g[tid] + bvec[tid];
}

// ================= embed + LN -> h_bf (bf16 residual stream) =================
__global__ __launch_bounds__(512) void embed_ln_kernel(
    const int* __restrict__ timesteps,
    const float* __restrict__ state0, const float* __restrict__ state1,
    const float* __restrict__ actions, const float* __restrict__ time_emb,
    const float* __restrict__ Ws, const float* __restrict__ bs,
    const float* __restrict__ Wa, const float* __restrict__ ba,
    const float* __restrict__ eg, const float* __restrict__ eb,
    __bf16* __restrict__ h_bf)
{
    __shared__ float xs[SDIM];
    __shared__ float red[16];
    int row = blockIdx.x;
    int b = row / SS;
    int pos = row - b * SS;
    int i = pos / 3;
    int t = pos - i * 3;
    int col = threadIdx.x;

    const float* x; const float* W; const float* bias; int K;
    if (t == 0)      { x = state0  + (size_t)(b*TT + i) * SDIM; W = Ws; bias = bs; K = SDIM; }
    else if (t == 1) { x = state1  + (size_t)(b*TT + i) * SDIM; W = Ws; bias = bs; K = SDIM; }
    else             { x = actions + (size_t)(b*TT + i) * ADIM; W = Wa; bias = ba; K = ADIM; }

    if (col < K) xs[col] = x[col];
    __syncthreads();

    int ts = timesteps[b*TT + i];
    float acc = bias[col] + time_emb[(size_t)ts * HDIM + col];
    for (int kk = 0; kk < K; ++kk)
        acc += xs[kk] * W[(size_t)kk * HDIM + col];

    float y = block_ln2(acc, col, eg, eb, red);
    h_bf[(size_t)row * HDIM + col] = f2b(y);
}

// ================= residual add + LN, bf16 in/out =================
__global__ __launch_bounds__(512) void ln_add_kernel(
    __bf16* __restrict__ h_bf, const __bf16* __restrict__ y,
    const float* __restrict__ g, const float* __restrict__ bvec)
{
    __shared__ float red[16];
    int row = blockIdx.x, col = threadIdx.x;
    size_t idx = (size_t)row * HDIM + col;
    float val = (float)h_bf[idx] + (float)y[idx];
    float o = block_ln2(val, col, g, bvec, red);
    h_bf[idx] = f2b(o);
}

// ================= weight pack: fp32 [K][N] -> bf16 [N][K] =================
__global__ __launch_bounds__(256) void pack_kernel(
    const float* __restrict__ wq, const float* __restrict__ wk,
    const float* __restrict__ wv, const float* __restrict__ wo,
    const float* __restrict__ w1, const float* __restrict__ w2,
    const float* __restrict__ bq_, const float* __restrict__ bk_, const float* __restrict__ bv_,
    __bf16* __restrict__ wqkvT, __bf16* __restrict__ woT,
    __bf16* __restrict__ w1T, __bf16* __restrict__ w2T, float* __restrict__ biasq)
{
    int bid = blockIdx.x;
    int tid = threadIdx.x;
    if (bid == 768) {
        for (int i = tid; i < 1536; i += 256)
            biasq[i] = (i < 512) ? bq_[i] : ((i < 1024) ? bk_[i-512] : bv_[i-1024]);
        return;
    }
    __shared__ float Ls[64][65];
    const float* src; __bf16* dst; int K, N, kt, nt;
    if (bid < 192) {
        int sec = bid / 64, t = bid % 64;
        src = (sec == 0) ? wq : (sec == 1) ? wk : wv;
        dst = wqkvT + (size_t)sec * 512 * 512;
        K = 512; N = 512; nt = t >> 3; kt = t & 7;
    } else if (bid < 256) {
        int t = bid - 192; src = wo; dst = woT; K = 512; N = 512; nt = t >> 3; kt = t & 7;
    } else if (bid < 512) {
        int t = bid - 256; src = w1; dst = w1T; K = 512; N = 2048; nt = t >> 3; kt = t & 7;
    } else {
        int t = bid - 512; src = w2; dst = w2T; K = 2048; N = 512; nt = t & 7; kt = t >> 3;
    }
    int k0 = kt * 64, n0 = nt * 64;
    int rr = tid >> 4, cc = (tid & 15) * 4;
    #pragma unroll
    for (int p = 0; p < 4; ++p) {
        float4 v = *(const float4*)(src + (size_t)(k0 + rr + p*16) * N + n0 + cc);
        Ls[rr + p*16][cc] = v.x; Ls[rr + p*16][cc+1] = v.y;
        Ls[rr + p*16][cc+2] = v.z; Ls[rr + p*16][cc+3] = v.w;
    }
    __syncthreads();
    int nn = tid >> 3, kc = (tid & 7) * 8;
    #pragma unroll
    for (int p = 0; p < 2; ++p) {
        __bf16 t8[8];
        #pragma unroll
        for (int t2 = 0; t2 < 8; ++t2) t8[t2] = f2b(Ls[kc + t2][nn + p*32]);
        *(uint4*)(dst + (size_t)(n0 + nn + p*32) * K + k0 + kc) = *(uint4*)t8;
    }
}

// ================= bf16 MFMA GEMM, double-buffered async LDS staging =================
// A: bf16 [M][lda].  Bt: bf16 [N][K].  C: bf16 [M][ldc].
// VTMODE: blocks with n0 >= 1024 write their tile TRANSPOSED to VTout
// (VT[(b*NH+h)*64 + d][SS]) via an LDS transpose reusing the staging LDS.
template<int MT, bool VTMODE>
__global__ __launch_bounds__(256) void gemm_mfma(
    const __bf16* __restrict__ A, const __bf16* __restrict__ Bt,
    const float* __restrict__ bias, __bf16* __restrict__ C,
    __bf16* __restrict__ VTout,
    int N, int K, int lda, int ldc, int gelu)
{
    constexpr int MI = MT / 32;
    constexpr int SMB = 2*MT*64 + 2*128*64;      // staging bytes (>= 32768 when MT=128)
    __shared__ __align__(16) char sm[SMB];
    __bf16* As = (__bf16*)sm;                    // [2][MT][32]
    __bf16* Bs = (__bf16*)(sm + 2*MT*64);        // [2][128][32]
    int tid = threadIdx.x;
    int wave = tid >> 6, lane = tid & 63;
    int l15 = lane & 15, quad = lane >> 4;
    int wy = wave >> 1, wx = wave & 1;
    int m0 = blockIdx.y * MT, n0 = blockIdx.x * 128;

    int srow = lane >> 2;
    int clog = (lane & 3) ^ ((lane >> 3) & 3);
    int pchunk = (quad ^ ((l15 >> 1) & 3)) * 8;

    f32x4 acc[MI][4];
    #pragma unroll
    for (int i = 0; i < MI; ++i)
        #pragma unroll
        for (int j = 0; j < 4; ++j) acc[i][j] = (f32x4){0.f,0.f,0.f,0.f};

    const __bf16* Abase = A  + (size_t)m0 * lda + clog * 8;
    const __bf16* Bbase = Bt + (size_t)n0 * K   + clog * 8;
    int NK = K >> 5;

    // prologue: stage k-tile 0 into buffer 0
    #pragma unroll
    for (int q = 0; q < MT/64; ++q) {
        int r0 = (wave * (MT/64) + q) * 16;
        gll16(Abase + (size_t)(r0 + srow) * lda, As + r0*32);
    }
    #pragma unroll
    for (int q = 0; q < 2; ++q) {
        int r0 = (wave * 2 + q) * 16;
        gll16(Bbase + (size_t)(r0 + srow) * K, Bs + r0*32);
    }

    for (int kt = 0; kt < NK; ++kt) {
        int buf = kt & 1;
        __syncthreads();   // drains the loads for `buf` (issued one full iter ago)
        if (kt + 1 < NK) {
            int k0 = (kt + 1) << 5;
            #pragma unroll
            for (int q = 0; q < MT/64; ++q) {
                int r0 = (wave * (MT/64) + q) * 16;
                gll16(Abase + (size_t)(r0 + srow) * lda + k0, As + ((buf^1)*MT + r0)*32);
            }
            #pragma unroll
            for (int q = 0; q < 2; ++q) {
                int r0 = (wave * 2 + q) * 16;
                gll16(Bbase + (size_t)(r0 + srow) * K + k0, Bs + ((buf^1)*128 + r0)*32);
            }
        }
        bf16x8 af[MI], bf[4];
        #pragma unroll
        for (int i = 0; i < MI; ++i)
            af[i] = *(const bf16x8*)&As[(buf*MT + wy*(MT/2) + i*16 + l15)*32 + pchunk];
        #pragma unroll
        for (int j = 0; j < 4; ++j)
            bf[j] = *(const bf16x8*)&Bs[(buf*128 + wx*64 + j*16 + l15)*32 + pchunk];
        #pragma unroll
        for (int i = 0; i < MI; ++i)
            #pragma unroll
            for (int j = 0; j < 4; ++j)
                acc[i][j] = __builtin_amdgcn_mfma_f32_16x16x32_bf16(af[i], bf[j], acc[i][j], 0, 0, 0);
    }

    if (VTMODE && n0 >= 1024) {
        // transpose tile (128 s x 128 d) into VT via LDS (reuse staging, 32 KB)
        __syncthreads();
        __bf16* T = (__bf16*)sm;          // logical [128 d][128 s], s-chunk swizzled
        #pragma unroll
        for (int j = 0; j < 4; ++j) {
            int dl = wx*64 + j*16 + l15;
            float bv = bias[n0 + dl];
            int x31 = dl & 31;
            #pragma unroll
            for (int i = 0; i < MI; ++i) {
                int sc = wy*16 + i*4 + quad;          // 4-elem s-chunk index
                int phys = sc ^ x31;
                __bf16 v4[4];
                #pragma unroll
                for (int r = 0; r < 4; ++r) v4[r] = f2b(acc[i][j][r] + bv);
                *(uint2*)(T + dl*128 + phys*4) = *(uint2*)v4;
            }
        }
        __syncthreads();
        int dl = tid >> 1, sh = (tid & 1) * 64;
        int dglob = n0 - 1024 + dl;
        int bb = m0 / SS, srel = m0 - bb*SS;
        __bf16* vb = VTout + ((size_t)(bb*NH + (dglob >> 6)) * 64 + (dglob & 63)) * SS + srel + sh;
        int x31 = dl & 31;
        #pragma unroll
        for (int u = 0; u < 8; ++u) {
            int c0 = (sh >> 2) + u*2;
            uint2 lo = *(const uint2*)(T + dl*128 + ((c0    ) ^ x31)*4);
            uint2 hi = *(const uint2*)(T + dl*128 + ((c0 + 1) ^ x31)*4);
            uint4 o; o.x = lo.x; o.y = lo.y; o.z = hi.x; o.w = hi.y;
            *(uint4*)(vb + u*8) = o;
        }
        return;
    }

    #pragma unroll
    for (int j = 0; j < 4; ++j) {
        int cc = n0 + wx*64 + j*16 + l15;
        float bv = bias[cc];
        #pragma unroll
        for (int i = 0; i < MI; ++i) {
            #pragma unroll
            for (int r = 0; r < 4; ++r) {
                int rr = m0 + wy*(MT/2) + i*16 + quad*4 + r;
                float v = acc[i][j][r] + bv;
                if (gelu) v = 0.5f * v * (1.f + erff(v * 0.70710678118654752f));
                C[(size_t)rr * ldc + cc] = f2b(v);
            }
        }
    }
}

// ================= S^T-layout MFMA flash attention, LDS-shared K/V =================
#define SM_C 0.18033688011112042f   // (1/8) * log2(e)

struct KVfrags { bf16x8 k00, k01, k10, k11, v0, v1, v2, v3; };

__device__ __forceinline__ unsigned pack2bf(float a, float b)
{
    union { __bf16 h[2]; unsigned u; } t;
    t.h[0] = (__bf16)a; t.h[1] = (__bf16)b;
    return t.u;
}

struct AttnState {
    f32x4 o0, o1, o2, o3;
    float m, l;
};

__device__ __forceinline__ void attn_step(AttnState& st, const KVfrags& kv,
                                          bf16x8 qf0, bf16x8 qf1,
                                          int kb, int qrow0, int lane)
{
    int l15 = lane & 15, quad = lane >> 4;
    f32x4 s0 = {0.f,0.f,0.f,0.f}, s1 = {0.f,0.f,0.f,0.f};
    s0 = __builtin_amdgcn_mfma_f32_16x16x32_bf16(kv.k00, qf0, s0, 0, 0, 0);
    s0 = __builtin_amdgcn_mfma_f32_16x16x32_bf16(kv.k01, qf1, s0, 0, 0, 0);
    s1 = __builtin_amdgcn_mfma_f32_16x16x32_bf16(kv.k10, qf0, s1, 0, 0, 0);
    s1 = __builtin_amdgcn_mfma_f32_16x16x32_bf16(kv.k11, qf1, s1, 0, 0, 0);

    if (kb + 31 > qrow0) {          // wave-uniform: tile straddles diagonal
        int qrow = qrow0 + l15;
        #pragma unroll
        for (int r = 0; r < 4; ++r) {
            int c0 = kb + quad*4 + r;
            if (c0 > qrow)      s0[r] = -1e30f;
            if (c0 + 16 > qrow) s1[r] = -1e30f;
        }
    }

    float tm = fmaxf(fmaxf(fmaxf(s0[0], s0[1]), fmaxf(s0[2], s0[3])),
                     fmaxf(fmaxf(s1[0], s1[1]), fmaxf(s1[2], s1[3])));
    tm = fmaxf(tm, __shfl_xor(tm, 16));
    tm = fmaxf(tm, __shfl_xor(tm, 32));
    float mnew = fmaxf(st.m, tm);
    float alpha = __builtin_amdgcn_exp2f((st.m - mnew) * SM_C);

    float p0[4], p1[4], rs = 0.f;
    #pragma unroll
    for (int r = 0; r < 4; ++r) {
        p0[r] = __builtin_amdgcn_exp2f((s0[r] - mnew) * SM_C);
        p1[r] = __builtin_amdgcn_exp2f((s1[r] - mnew) * SM_C);
        rs += p0[r] + p1[r];
    }
    rs += __shfl_xor(rs, 16);
    rs += __shfl_xor(rs, 32);
    st.l = st.l * alpha + rs;
    st.m = mnew;
    st.o0 *= alpha; st.o1 *= alpha; st.o2 *= alpha; st.o3 *= alpha;

    // P^T -> PV B-frag; all shuffles at full wave exec, per-lane cndmask after.
    unsigned pk0a = pack2bf(p0[0], p0[1]), pk0b = pack2bf(p0[2], p0[3]);
    unsigned pk1a = pack2bf(p1[0], p1[1]), pk1b = pack2bf(p1[2], p1[3]);
    int sA = l15 + (quad & 1) * 32;
    int sB = sA + 16;
    int hi = quad >> 1;
    unsigned a0A = (unsigned)__shfl((int)pk0a, sA);
    unsigned a1A = (unsigned)__shfl((int)pk1a, sA);
    unsigned b0A = (unsigned)__shfl((int)pk0b, sA);
    unsigned b1A = (unsigned)__shfl((int)pk1b, sA);
    unsigned a0B = (unsigned)__shfl((int)pk0a, sB);
    unsigned a1B = (unsigned)__shfl((int)pk1a, sB);
    unsigned b0B = (unsigned)__shfl((int)pk0b, sB);
    unsigned b1B = (unsigned)__shfl((int)pk1b, sB);
    union { unsigned u[4]; bf16x8 v; } pb;
    pb.u[0] = hi ? a1A : a0A;
    pb.u[1] = hi ? b1A : b0A;
    pb.u[2] = hi ? a1B : a0B;
    pb.u[3] = hi ? b1B : b0B;

    st.o0 = __builtin_amdgcn_mfma_f32_16x16x32_bf16(kv.v0, pb.v, st.o0, 0, 0, 0);
    st.o1 = __builtin_amdgcn_mfma_f32_16x16x32_bf16(kv.v1, pb.v, st.o1, 0, 0, 0);
    st.o2 = __builtin_amdgcn_mfma_f32_16x16x32_bf16(kv.v2, pb.v, st.o2, 0, 0, 0);
    st.o3 = __builtin_amdgcn_mfma_f32_16x16x32_bf16(kv.v3, pb.v, st.o3, 0, 0, 0);
}

// grid: 768 blocks (region-interleaved qt), 256 threads; block shares K/V via LDS.
// qkc: [row][1024] = q|k; ctx output overwrites the q-section (disjoint
// (row, head-col) ownership: each block reads exactly the q slice it writes).
__global__ __launch_bounds__(256, 3) void attn_kernel(
    __bf16* qkc, const __bf16* __restrict__ VT)
{
    __shared__ __align__(16) char smem[24576];

    int x = blockIdx.x;
    int region = x >> 8;          // 0,1,2
    int j = x & 255;
    int i = j >> 5;               // 0..7
    int hb = j & 31;
    int qt = (region == 0) ? i : (region == 1) ? (15 - i) : (16 + i);
    int h = hb >> 2, b = hb & 3;

    int tid = threadIdx.x;
    int w = tid >> 6, lane = tid & 63;
    int l15 = lane & 15, quad = lane >> 4;
    int qrow0 = qt * 64 + w * 16;

    const __bf16* qp = qkc + (size_t)(b*SS + qrow0 + l15) * 1024 + h*64 + quad*8;
    bf16x8 qf0 = *(const bf16x8*)qp;
    bf16x8 qf1 = *(const bf16x8*)(qp + 32);

    // staging bases
    const __bf16* kgbase = qkc + (size_t)(b*SS) * 1024 + 512 + h*64;     // + row*1024
    const __bf16* vgbase = VT + (size_t)(b*NH + h) * 64 * SS;            // + row*SS
    int ksrow = lane >> 3;                       // 0..7
    int kclog = (lane & 7) ^ ((lane >> 3) & 7);
    int vsrow = lane >> 2;                       // 0..15
    int vclog = (lane & 3) ^ ((lane >> 3) & 3);

    // frag-read swizzled chunk offsets
    int swkA = (quad ^ (l15 & 7)) * 8;
    int swkB = ((quad + 4) ^ (l15 & 7)) * 8;
    int swv  = (quad ^ ((l15 >> 1) & 3)) * 8;

    AttnState st;
    st.o0 = (f32x4){0.f,0.f,0.f,0.f}; st.o1 = st.o0; st.o2 = st.o0; st.o3 = st.o0;
    st.m = -1e30f; st.l = 0.f;

    int mynkt = (qrow0 + 47) >> 5;
    int nkt_max = 2*qt + 2;

    // stage tile 0 into buffer 0
    gll16(kgbase + (size_t)(w*8 + ksrow) * 1024 + kclog*8, (__bf16*)smem + (w*8)*64);
    gll16(vgbase + (size_t)(w*16 + vsrow) * SS + vclog*8,  (__bf16*)(smem + 16384) + (w*16)*32);
    __syncthreads();

    for (int jt = 0; jt < nkt_max; ++jt) {
        int buf = jt & 1;
        __bf16* Kb = (__bf16*)(smem + buf * 8192);
        __bf16* Vb = (__bf16*)(smem + 16384 + buf * 4096);
        __bf16* Kn = (__bf16*)(smem + (buf ^ 1) * 8192);
        __bf16* Vn = (__bf16*)(smem + 16384 + (buf ^ 1) * 4096);
        if (jt + 1 < nkt_max) {
            int kb = (jt + 1) * 32;
            gll16(kgbase + (size_t)(kb + w*8 + ksrow) * 1024 + kclog*8, Kn + (w*8)*64);
            gll16(vgbase + (size_t)(w*16 + vsrow) * SS + kb + vclog*8,  Vn + (w*16)*32);
        }
        if (jt < mynkt) {
            KVfrags f;
            f.k00 = *(const bf16x8*)(Kb + l15*64 + swkA);
            f.k01 = *(const bf16x8*)(Kb + l15*64 + swkB);
            f.k10 = *(const bf16x8*)(Kb + (16+l15)*64 + swkA);
            f.k11 = *(const bf16x8*)(Kb + (16+l15)*64 + swkB);
            f.v0  = *(const bf16x8*)(Vb + l15*32 + swv);
            f.v1  = *(const bf16x8*)(Vb + (16+l15)*32 + swv);
            f.v2  = *(const bf16x8*)(Vb + (32+l15)*32 + swv);
            f.v3  = *(const bf16x8*)(Vb + (48+l15)*32 + swv);
            attn_step(st, f, qf0, qf1, jt * 32, qrow0, lane);
        }
        __syncthreads();
    }

    // epilogue: O^T regs -> LDS (aliases staging; all compute done) -> stores
    float* otw = (float*)smem + w * 16 * 68;    // 4*16*68*4 = 17408 B total
    float inv = 1.f / st.l;
    #pragma unroll
    for (int r = 0; r < 4; ++r) {
        otw[l15*68 +  0 + quad*4 + r] = st.o0[r] * inv;
        otw[l15*68 + 16 + quad*4 + r] = st.o1[r] * inv;
        otw[l15*68 + 32 + quad*4 + r] = st.o2[r] * inv;
        otw[l15*68 + 48 + quad*4 + r] = st.o3[r] * inv;
    }
    asm volatile("s_waitcnt lgkmcnt(0)" ::: "memory");
    int row = lane >> 2, ch = (lane & 3) * 16;
    union { __bf16 hh[16]; uint4 q4[2]; } ob;
    #pragma unroll
    for (int t2 = 0; t2 < 16; ++t2) ob.hh[t2] = f2b(otw[row*68 + ch + t2]);
    __bf16* cp = qkc + (size_t)(b*SS + qrow0 + row) * 1024 + h*64 + ch;
    *(uint4*)cp = ob.q4[0];
    *(uint4*)(cp + 8) = ob.q4[1];
}

// ================= final projection (bf16 h) =================
__global__ __launch_bounds__(256) void proj_kernel(
    const __bf16* __restrict__ h_bf, const float* __restrict__ Wp,
    const float* __restrict__ bp, float* __restrict__ out)
{
    int rid = blockIdx.x * 8 + (threadIdx.x >> 5);
    int col = threadIdx.x & 31;
    int b = rid / TT, i = rid - b * TT;
    const __bf16* x = h_bf + ((size_t)(b*SS) + 3*i + 1) * HDIM;
    float acc = bp[col];
    for (int kk = 0; kk < HDIM; ++kk)
        acc += (float)x[kk] * Wp[kk * ADIM + col];
    out[(size_t)rid * ADIM + col] = acc;
}

extern "C" void kernel_launch(void* const* d_in, const int* in_sizes, int n_in,
                              void* d_out, int out_size, void* d_ws, size_t ws_size,
                              hipStream_t stream)
{
    (void)in_sizes; (void)n_in; (void)out_size; (void)ws_size;
    const int*   timesteps = (const int*)  d_in[0];
    const float* state0    = (const float*)d_in[1];
    const float* state1    = (const float*)d_in[2];
    const float* actions   = (const float*)d_in[3];
    const float* time_emb  = (const float*)d_in[4];
    const float* Ws  = (const float*)d_in[5];
    const float* bs  = (const float*)d_in[6];
    const float* Wa  = (const float*)d_in[7];
    const float* ba  = (const float*)d_in[8];
    const float* Wq  = (const float*)d_in[9];
    const float* bq  = (const float*)d_in[10];
    const float* Wk  = (const float*)d_in[11];
    const float* bk  = (const float*)d_in[12];
    const float* Wv  = (const float*)d_in[13];
    const float* bv  = (const float*)d_in[14];
    const float* Wo  = (const float*)d_in[15];
    const float* bo  = (const float*)d_in[16];
    const float* W1  = (const float*)d_in[17];
    const float* b1  = (const float*)d_in[18];
    const float* W2  = (const float*)d_in[19];
    const float* b2  = (const float*)d_in[20];
    const float* ln1g = (const float*)d_in[21];
    const float* ln1b = (const float*)d_in[22];
    const float* ln2g = (const float*)d_in[23];
    const float* ln2b = (const float*)d_in[24];
    const float* elng = (const float*)d_in[25];
    const float* elnb = (const float*)d_in[26];
    const float* Wp   = (const float*)d_in[27];
    const float* bp   = (const float*)d_in[28];
    float* out = (float*)d_out;

    const size_t SZ = (size_t)MS * HDIM;          // 3,145,728
    char* p = (char*)d_ws;
    __bf16* h_bf = (__bf16*)p;           p += SZ * 2;                  // residual (bf16)
    __bf16* qk   = (__bf16*)p;           p += (size_t)MS * 1024 * 2;   // q|k; q-sec doubles as ctx
    __bf16* VT   = (__bf16*)p;           p += SZ * 2;
    /* hid extension */                  p += SZ * 2;                  // hid = qk..VT..ext (MSx2048)
    __bf16* tmp_bf = (__bf16*)p;         p += SZ * 2;
    __bf16* wqkvT = (__bf16*)p;          p += (size_t)1536 * 512 * 2;
    __bf16* woT   = (__bf16*)p;          p += (size_t)512 * 512 * 2;
    __bf16* w1T   = (__bf16*)p;          p += (size_t)2048 * 512 * 2;
    __bf16* w2T   = (__bf16*)p;          p += (size_t)512 * 2048 * 2;
    float*  biasq = (float*)p;           p += 1536 * 4;
    __bf16* hid   = qk;                  // MS x 2048 bf16 spans qk+VT+ext

    embed_ln_kernel<<<MS, 512, 0, stream>>>(timesteps, state0, state1, actions, time_emb,
                                            Ws, bs, Wa, ba, elng, elnb, h_bf);

    dim3 gQKV(1536/128, MS/128);   // 12 x 48
    dim3 gO  (512/128,  MS/64);    // 4 x 96  (64-row tiles)
    dim3 gF1 (2048/128, MS/128);   // 16 x 48

    for (int lyr = 0; lyr < NBLK; ++lyr) {
        const float* wq = Wq + (size_t)lyr * HDIM * HDIM;
        const float* wk = Wk + (size_t)lyr * HDIM * HDIM;
        const float* wv = Wv + (size_t)lyr * HDIM * HDIM;
        const float* wo = Wo + (size_t)lyr * HDIM * HDIM;
        const float* w1 = W1 + (size_t)lyr * HDIM * DFF;
        const float* w2 = W2 + (size_t)lyr * DFF * HDIM;

        pack_kernel<<<769, 256, 0, stream>>>(wq, wk, wv, wo, w1, w2,
                                             bq + lyr*HDIM, bk + lyr*HDIM, bv + lyr*HDIM,
                                             wqkvT, woT, w1T, w2T, biasq);
        // QKV: q|k rows -> qk (ldc 1024); V tiles transposed -> VT in-epilogue
        gemm_mfma<128, true><<<gQKV, 256, 0, stream>>>(h_bf, wqkvT, biasq, qk, VT,
                                                       1536, HDIM, HDIM, 1024, 0);
        attn_kernel<<<dim3(768), 256, 0, stream>>>(qk, VT);
        // WO: A = ctx (q-section, lda 1024)
        gemm_mfma<64, false><<<gO, 256, 0, stream>>>(qk, woT, bo + lyr*HDIM, tmp_bf, nullptr,
                                                     HDIM, HDIM, 1024, HDIM, 0);
        ln_add_kernel<<<MS, 512, 0, stream>>>(h_bf, tmp_bf, ln1g + lyr*HDIM, ln1b + lyr*HDIM);
        gemm_mfma<128, false><<<gF1, 256, 0, stream>>>(h_bf, w1T, b1 + lyr*DFF, hid, nullptr,
                                                       DFF, HDIM, HDIM, DFF, 1);
        gemm_mfma<64, false><<<gO, 256, 0, stream>>>(hid, w2T, b2 + lyr*HDIM, tmp_bf, nullptr,
                                                     HDIM, DFF, DFF, HDIM, 0);
        ln_add_kernel<<<MS, 512, 0, stream>>>(h_bf, tmp_bf, ln2g + lyr*HDIM, ln2b + lyr*HDIM);
    }

    proj_kernel<<<(BB*TT)/8, 256, 0, stream>>>(h_bf, Wp, bp, out);
}

// Round 10
// 1146.453 us; speedup vs baseline: 1.4518x; 1.0446x over previous
//
#include <hip/hip_runtime.h>
#include <hip/hip_bf16.h>
#include <math.h>

#define BB 4
#define TT 512
#define SDIM 64
#define ADIM 32
#define HDIM 512
#define NH 8
#define NBLK 6
#define DFF 2048
#define SS 1536          // 3*T
#define DH 64
#define MS (BB*SS)       // 6144 rows

typedef __attribute__((ext_vector_type(8))) __bf16 bf16x8;
typedef __attribute__((ext_vector_type(4))) float f32x4;

__device__ __forceinline__ __bf16 f2b(float x) { return (__bf16)x; }

// async global->LDS, 16 B per lane; LDS dest = wave-uniform base + lane*16
__device__ __forceinline__ void gll16(const void* g, void* l) {
    __builtin_amdgcn_global_load_lds(
        (const __attribute__((address_space(1))) unsigned int*)g,
        (__attribute__((address_space(3))) unsigned int*)l, 16, 0, 0);
}

// ================= shuffle-based LN over 512 threads =================
__device__ __forceinline__ float block_ln2(float val, int tid,
                                           const float* __restrict__ g,
                                           const float* __restrict__ bvec,
                                           float* red)
{
    float s = val, sq = val * val;
    #pragma unroll
    for (int off = 32; off; off >>= 1) { s += __shfl_xor(s, off); sq += __shfl_xor(sq, off); }
    int w = tid >> 6;
    if ((tid & 63) == 0) { red[w] = s; red[8 + w] = sq; }
    __syncthreads();
    float S = 0.f, SQ = 0.f;
    #pragma unroll
    for (int i = 0; i < 8; ++i) { S += red[i]; SQ += red[8 + i]; }
    float mean = S * (1.f / HDIM);
    float var  = SQ * (1.f / HDIM) - mean * mean;
    return (val - mean) * rsqrtf(var + 1e-5f) * g[tid] + bvec[tid];
}

// ================= embed + LN -> h_bf (bf16 residual stream) =================
__global__ __launch_bounds__(512) void embed_ln_kernel(
    const int* __restrict__ timesteps,
    const float* __restrict__ state0, const float* __restrict__ state1,
    const float* __restrict__ actions, const float* __restrict__ time_emb,
    const float* __restrict__ Ws, const float* __restrict__ bs,
    const float* __restrict__ Wa, const float* __restrict__ ba,
    const float* __restrict__ eg, const float* __restrict__ eb,
    __bf16* __restrict__ h_bf)
{
    __shared__ float xs[SDIM];
    __shared__ float red[16];
    int row = blockIdx.x;
    int b = row / SS;
    int pos = row - b * SS;
    int i = pos / 3;
    int t = pos - i * 3;
    int col = threadIdx.x;

    const float* x; const float* W; const float* bias; int K;
    if (t == 0)      { x = state0  + (size_t)(b*TT + i) * SDIM; W = Ws; bias = bs; K = SDIM; }
    else if (t == 1) { x = state1  + (size_t)(b*TT + i) * SDIM; W = Ws; bias = bs; K = SDIM; }
    else             { x = actions + (size_t)(b*TT + i) * ADIM; W = Wa; bias = ba; K = ADIM; }

    if (col < K) xs[col] = x[col];
    __syncthreads();

    int ts = timesteps[b*TT + i];
    float acc = bias[col] + time_emb[(size_t)ts * HDIM + col];
    for (int kk = 0; kk < K; ++kk)
        acc += xs[kk] * W[(size_t)kk * HDIM + col];

    float y = block_ln2(acc, col, eg, eb, red);
    h_bf[(size_t)row * HDIM + col] = f2b(y);
}

// ================= residual add + LN, bf16 in/out =================
__global__ __launch_bounds__(512) void ln_add_kernel(
    __bf16* __restrict__ h_bf, const __bf16* __restrict__ y,
    const float* __restrict__ g, const float* __restrict__ bvec)
{
    __shared__ float red[16];
    int row = blockIdx.x, col = threadIdx.x;
    size_t idx = (size_t)row * HDIM + col;
    float val = (float)h_bf[idx] + (float)y[idx];
    float o = block_ln2(val, col, g, bvec, red);
    h_bf[idx] = f2b(o);
}

// ================= weight pack: fp32 [K][N] -> bf16 [N][K] =================
__global__ __launch_bounds__(256) void pack_kernel(
    const float* __restrict__ wq, const float* __restrict__ wk,
    const float* __restrict__ wv, const float* __restrict__ wo,
    const float* __restrict__ w1, const float* __restrict__ w2,
    const float* __restrict__ bq_, const float* __restrict__ bk_, const float* __restrict__ bv_,
    __bf16* __restrict__ wqkvT, __bf16* __restrict__ woT,
    __bf16* __restrict__ w1T, __bf16* __restrict__ w2T, float* __restrict__ biasq)
{
    int bid = blockIdx.x;
    int tid = threadIdx.x;
    if (bid == 768) {
        for (int i = tid; i < 1536; i += 256)
            biasq[i] = (i < 512) ? bq_[i] : ((i < 1024) ? bk_[i-512] : bv_[i-1024]);
        return;
    }
    __shared__ float Ls[64][65];
    const float* src; __bf16* dst; int K, N, kt, nt;
    if (bid < 192) {
        int sec = bid / 64, t = bid % 64;
        src = (sec == 0) ? wq : (sec == 1) ? wk : wv;
        dst = wqkvT + (size_t)sec * 512 * 512;
        K = 512; N = 512; nt = t >> 3; kt = t & 7;
    } else if (bid < 256) {
        int t = bid - 192; src = wo; dst = woT; K = 512; N = 512; nt = t >> 3; kt = t & 7;
    } else if (bid < 512) {
        int t = bid - 256; src = w1; dst = w1T; K = 512; N = 2048; nt = t >> 3; kt = t & 7;
    } else {
        int t = bid - 512; src = w2; dst = w2T; K = 2048; N = 512; nt = t & 7; kt = t >> 3;
    }
    int k0 = kt * 64, n0 = nt * 64;
    int rr = tid >> 4, cc = (tid & 15) * 4;
    #pragma unroll
    for (int p = 0; p < 4; ++p) {
        float4 v = *(const float4*)(src + (size_t)(k0 + rr + p*16) * N + n0 + cc);
        Ls[rr + p*16][cc] = v.x; Ls[rr + p*16][cc+1] = v.y;
        Ls[rr + p*16][cc+2] = v.z; Ls[rr + p*16][cc+3] = v.w;
    }
    __syncthreads();
    int nn = tid >> 3, kc = (tid & 7) * 8;
    #pragma unroll
    for (int p = 0; p < 2; ++p) {
        __bf16 t8[8];
        #pragma unroll
        for (int t2 = 0; t2 < 8; ++t2) t8[t2] = f2b(Ls[kc + t2][nn + p*32]);
        *(uint4*)(dst + (size_t)(n0 + nn + p*32) * K + k0 + kc) = *(uint4*)t8;
    }
}

// ================= bf16 MFMA GEMM, double-buffered async LDS staging =================
// A: bf16 [M][lda].  Bt: bf16 [N][K].  C: bf16 [M][ldc].
// VTMODE: blocks with n0 >= 1024 write their tile TRANSPOSED to VTout
// (VT[(b*NH+h)*64 + d][SS]) via an LDS transpose reusing the staging LDS.
template<int MT, bool VTMODE>
__global__ __launch_bounds__(256) void gemm_mfma(
    const __bf16* __restrict__ A, const __bf16* __restrict__ Bt,
    const float* __restrict__ bias, __bf16* __restrict__ C,
    __bf16* __restrict__ VTout,
    int N, int K, int lda, int ldc, int gelu)
{
    constexpr int MI = MT / 32;
    constexpr int SMB = 2*MT*64 + 2*128*64;      // staging bytes (>= 32768 when MT=128)
    __shared__ __align__(16) char sm[SMB];
    __bf16* As = (__bf16*)sm;                    // [2][MT][32]
    __bf16* Bs = (__bf16*)(sm + 2*MT*64);        // [2][128][32]
    int tid = threadIdx.x;
    int wave = tid >> 6, lane = tid & 63;
    int l15 = lane & 15, quad = lane >> 4;
    int wy = wave >> 1, wx = wave & 1;
    int m0 = blockIdx.y * MT, n0 = blockIdx.x * 128;

    int srow = lane >> 2;
    int clog = (lane & 3) ^ ((lane >> 3) & 3);
    int pchunk = (quad ^ ((l15 >> 1) & 3)) * 8;

    f32x4 acc[MI][4];
    #pragma unroll
    for (int i = 0; i < MI; ++i)
        #pragma unroll
        for (int j = 0; j < 4; ++j) acc[i][j] = (f32x4){0.f,0.f,0.f,0.f};

    const __bf16* Abase = A  + (size_t)m0 * lda + clog * 8;
    const __bf16* Bbase = Bt + (size_t)n0 * K   + clog * 8;
    int NK = K >> 5;

    // prologue: stage k-tile 0 into buffer 0
    #pragma unroll
    for (int q = 0; q < MT/64; ++q) {
        int r0 = (wave * (MT/64) + q) * 16;
        gll16(Abase + (size_t)(r0 + srow) * lda, As + r0*32);
    }
    #pragma unroll
    for (int q = 0; q < 2; ++q) {
        int r0 = (wave * 2 + q) * 16;
        gll16(Bbase + (size_t)(r0 + srow) * K, Bs + r0*32);
    }

    for (int kt = 0; kt < NK; ++kt) {
        int buf = kt & 1;
        __syncthreads();   // drains the loads for `buf` (issued one full iter ago)
        if (kt + 1 < NK) {
            int k0 = (kt + 1) << 5;
            #pragma unroll
            for (int q = 0; q < MT/64; ++q) {
                int r0 = (wave * (MT/64) + q) * 16;
                gll16(Abase + (size_t)(r0 + srow) * lda + k0, As + ((buf^1)*MT + r0)*32);
            }
            #pragma unroll
            for (int q = 0; q < 2; ++q) {
                int r0 = (wave * 2 + q) * 16;
                gll16(Bbase + (size_t)(r0 + srow) * K + k0, Bs + ((buf^1)*128 + r0)*32);
            }
        }
        bf16x8 af[MI], bf[4];
        #pragma unroll
        for (int i = 0; i < MI; ++i)
            af[i] = *(const bf16x8*)&As[(buf*MT + wy*(MT/2) + i*16 + l15)*32 + pchunk];
        #pragma unroll
        for (int j = 0; j < 4; ++j)
            bf[j] = *(const bf16x8*)&Bs[(buf*128 + wx*64 + j*16 + l15)*32 + pchunk];
        #pragma unroll
        for (int i = 0; i < MI; ++i)
            #pragma unroll
            for (int j = 0; j < 4; ++j)
                acc[i][j] = __builtin_amdgcn_mfma_f32_16x16x32_bf16(af[i], bf[j], acc[i][j], 0, 0, 0);
    }

    if (VTMODE && n0 >= 1024) {
        // transpose tile (128 s x 128 d) into VT via LDS (reuse staging, 32 KB)
        __syncthreads();
        __bf16* T = (__bf16*)sm;          // logical [128 d][128 s], s-chunk swizzled
        #pragma unroll
        for (int j = 0; j < 4; ++j) {
            int dl = wx*64 + j*16 + l15;
            float bv = bias[n0 + dl];
            int x31 = dl & 31;
            #pragma unroll
            for (int i = 0; i < MI; ++i) {
                int sc = wy*16 + i*4 + quad;          // 4-elem s-chunk index
                int phys = sc ^ x31;
                __bf16 v4[4];
                #pragma unroll
                for (int r = 0; r < 4; ++r) v4[r] = f2b(acc[i][j][r] + bv);
                *(uint2*)(T + dl*128 + phys*4) = *(uint2*)v4;
            }
        }
        __syncthreads();
        int dl = tid >> 1, sh = (tid & 1) * 64;
        int dglob = n0 - 1024 + dl;
        int bb = m0 / SS, srel = m0 - bb*SS;
        __bf16* vb = VTout + ((size_t)(bb*NH + (dglob >> 6)) * 64 + (dglob & 63)) * SS + srel + sh;
        int x31 = dl & 31;
        #pragma unroll
        for (int u = 0; u < 8; ++u) {
            int c0 = (sh >> 2) + u*2;
            uint2 lo = *(const uint2*)(T + dl*128 + ((c0    ) ^ x31)*4);
            uint2 hi = *(const uint2*)(T + dl*128 + ((c0 + 1) ^ x31)*4);
            uint4 o; o.x = lo.x; o.y = lo.y; o.z = hi.x; o.w = hi.y;
            *(uint4*)(vb + u*8) = o;
        }
        return;
    }

    #pragma unroll
    for (int j = 0; j < 4; ++j) {
        int cc = n0 + wx*64 + j*16 + l15;
        float bv = bias[cc];
        #pragma unroll
        for (int i = 0; i < MI; ++i) {
            #pragma unroll
            for (int r = 0; r < 4; ++r) {
                int rr = m0 + wy*(MT/2) + i*16 + quad*4 + r;
                float v = acc[i][j][r] + bv;
                if (gelu) v = 0.5f * v * (1.f + erff(v * 0.70710678118654752f));
                C[(size_t)rr * ldc + cc] = f2b(v);
            }
        }
    }
}

// ================= S^T-layout MFMA flash attention, 64-row K-tiles =================
#define SM_C 0.18033688011112042f   // (1/8) * log2(e)

__device__ __forceinline__ unsigned pack2bf(float a, float b)
{
    union { __bf16 h[2]; unsigned u; } t;
    t.h[0] = (__bf16)a; t.h[1] = (__bf16)b;
    return t.u;
}

// P^T (two 16-row frags) -> PV B-frag. All shuffles at full wave exec,
// per-lane cndmask after (verified in rounds 4-9).
__device__ __forceinline__ bf16x8 ptrans(const float* p0, const float* p1, int lane)
{
    int l15 = lane & 15, quad = lane >> 4;
    unsigned pk0a = pack2bf(p0[0], p0[1]), pk0b = pack2bf(p0[2], p0[3]);
    unsigned pk1a = pack2bf(p1[0], p1[1]), pk1b = pack2bf(p1[2], p1[3]);
    int sA = l15 + (quad & 1) * 32;
    int sB = sA + 16;
    int hi = quad >> 1;
    unsigned a0A = (unsigned)__shfl((int)pk0a, sA);
    unsigned a1A = (unsigned)__shfl((int)pk1a, sA);
    unsigned b0A = (unsigned)__shfl((int)pk0b, sA);
    unsigned b1A = (unsigned)__shfl((int)pk1b, sA);
    unsigned a0B = (unsigned)__shfl((int)pk0a, sB);
    unsigned a1B = (unsigned)__shfl((int)pk1a, sB);
    unsigned b0B = (unsigned)__shfl((int)pk0b, sB);
    unsigned b1B = (unsigned)__shfl((int)pk1b, sB);
    union { unsigned u[4]; bf16x8 v; } pb;
    pb.u[0] = hi ? a1A : a0A;
    pb.u[1] = hi ? b1A : b0A;
    pb.u[2] = hi ? a1B : a0B;
    pb.u[3] = hi ? b1B : b0B;
    return pb.v;
}

// grid: 768 blocks (region-interleaved qt), 256 threads; block shares K/V via LDS.
// qkc: [row][1024] = q|k; ctx overwrites the q-section (disjoint ownership).
// LDS (32 KB): K tile [64 s][64 d] x2 bufs (16 KB), V^T tile [64 d][64 s] x2 (16 KB),
// both chunk-swizzled phys = c ^ (row & 7). nkt = qt+1, uniform across waves.
__global__ __launch_bounds__(256, 3) void attn_kernel(
    __bf16* qkc, const __bf16* __restrict__ VT)
{
    __shared__ __align__(16) char smem[32768];

    int x = blockIdx.x;
    int region = x >> 8;          // 0,1,2
    int j = x & 255;
    int i = j >> 5;               // 0..7
    int hb = j & 31;
    int qt = (region == 0) ? i : (region == 1) ? (15 - i) : (16 + i);
    int h = hb >> 2, b = hb & 3;

    int tid = threadIdx.x;
    int w = tid >> 6, lane = tid & 63;
    int l15 = lane & 15, quad = lane >> 4;
    int qrow0 = qt * 64 + w * 16;

    const __bf16* qp = qkc + (size_t)(b*SS + qrow0 + l15) * 1024 + h*64 + quad*8;
    bf16x8 qf0 = *(const bf16x8*)qp;
    bf16x8 qf1 = *(const bf16x8*)(qp + 32);

    // staging bases
    const __bf16* kgbase = qkc + (size_t)(b*SS) * 1024 + 512 + h*64;     // + srow*1024
    const __bf16* vgbase = VT + (size_t)(b*NH + h) * 64 * SS;            // + drow*SS
    int srow8 = lane >> 3;                        // 0..7
    int clog  = (lane & 7) ^ ((lane >> 3) & 7);   // logical chunk for DMA lane
    // frag-read swizzled chunk offsets: phys = (half*4 + quad) ^ (l15 & 7)
    int sw0 = ((0*4 + quad) ^ (l15 & 7)) * 8;
    int sw1 = ((1*4 + quad) ^ (l15 & 7)) * 8;

    f32x4 o0 = {0.f,0.f,0.f,0.f}, o1 = o0, o2 = o0, o3 = o0;
    float sm_m = -1e30f, sm_l = 0.f;

    int nkt = qt + 1;

    // stage tile 0 into buffer 0 (K: 2 issues/wave, V: 2 issues/wave)
    #pragma unroll
    for (int q = 0; q < 2; ++q) {
        int r0 = (w*2 + q) * 8;
        gll16(kgbase + (size_t)(r0 + srow8) * 1024 + clog*8, (__bf16*)smem + r0*64);
        gll16(vgbase + (size_t)(r0 + srow8) * SS   + clog*8, (__bf16*)(smem + 16384) + r0*64);
    }
    __syncthreads();

    for (int jt = 0; jt < nkt; ++jt) {
        int buf = jt & 1;
        const __bf16* Kb = (const __bf16*)(smem + buf * 8192);
        const __bf16* Vb = (const __bf16*)(smem + 16384 + buf * 8192);
        if (jt + 1 < nkt) {
            int kb2 = (jt + 1) * 64;
            __bf16* Kn = (__bf16*)(smem + (buf ^ 1) * 8192);
            __bf16* Vn = (__bf16*)(smem + 16384 + (buf ^ 1) * 8192);
            #pragma unroll
            for (int q = 0; q < 2; ++q) {
                int r0 = (w*2 + q) * 8;
                gll16(kgbase + (size_t)(kb2 + r0 + srow8) * 1024 + clog*8, Kn + r0*64);
                gll16(vgbase + (size_t)(r0 + srow8) * SS + kb2 + clog*8,   Vn + r0*64);
            }
        }
        int kb = jt * 64;

        // QK^T: 4 s-frags x (K=64 via 2 MFMAs)
        f32x4 s[4];
        #pragma unroll
        for (int f = 0; f < 4; ++f) {
            bf16x8 k0 = *(const bf16x8*)(Kb + (16*f + l15)*64 + sw0);
            bf16x8 k1 = *(const bf16x8*)(Kb + (16*f + l15)*64 + sw1);
            f32x4 sf = {0.f,0.f,0.f,0.f};
            sf = __builtin_amdgcn_mfma_f32_16x16x32_bf16(k0, qf0, sf, 0, 0, 0);
            sf = __builtin_amdgcn_mfma_f32_16x16x32_bf16(k1, qf1, sf, 0, 0, 0);
            s[f] = sf;
        }

        if (kb + 63 > qrow0) {          // wave-uniform: tile straddles diagonal
            int qrow = qrow0 + l15;
            #pragma unroll
            for (int f = 0; f < 4; ++f)
                #pragma unroll
                for (int r = 0; r < 4; ++r)
                    if (kb + 16*f + quad*4 + r > qrow) s[f][r] = -1e30f;
        }

        float tm = -1e30f;
        #pragma unroll
        for (int f = 0; f < 4; ++f)
            #pragma unroll
            for (int r = 0; r < 4; ++r) tm = fmaxf(tm, s[f][r]);
        tm = fmaxf(tm, __shfl_xor(tm, 16));
        tm = fmaxf(tm, __shfl_xor(tm, 32));
        float mnew = fmaxf(sm_m, tm);
        float alpha = __builtin_amdgcn_exp2f((sm_m - mnew) * SM_C);

        float pp[4][4];
        float rs = 0.f;
        #pragma unroll
        for (int f = 0; f < 4; ++f)
            #pragma unroll
            for (int r = 0; r < 4; ++r) {
                float pv = __builtin_amdgcn_exp2f((s[f][r] - mnew) * SM_C);
                pp[f][r] = pv;
                rs += pv;
            }
        rs += __shfl_xor(rs, 16);
        rs += __shfl_xor(rs, 32);
        sm_l = sm_l * alpha + rs;
        sm_m = mnew;
        o0 *= alpha; o1 *= alpha; o2 *= alpha; o3 *= alpha;

        bf16x8 pb01 = ptrans(pp[0], pp[1], lane);   // K rows kb..kb+31
        bf16x8 pb23 = ptrans(pp[2], pp[3], lane);   // K rows kb+32..kb+63

        #pragma unroll
        for (int ii = 0; ii < 4; ++ii) {
            bf16x8 va = *(const bf16x8*)(Vb + (16*ii + l15)*64 + sw0);
            bf16x8 vb = *(const bf16x8*)(Vb + (16*ii + l15)*64 + sw1);
            f32x4* op = (ii == 0) ? &o0 : (ii == 1) ? &o1 : (ii == 2) ? &o2 : &o3;
            *op = __builtin_amdgcn_mfma_f32_16x16x32_bf16(va, pb01, *op, 0, 0, 0);
            *op = __builtin_amdgcn_mfma_f32_16x16x32_bf16(vb, pb23, *op, 0, 0, 0);
        }
        __syncthreads();
    }

    // epilogue: O^T regs -> LDS (aliases staging; all compute done) -> stores
    float* otw = (float*)smem + w * 16 * 68;    // 4*16*68*4 = 17408 B total
    float inv = 1.f / sm_l;
    #pragma unroll
    for (int r = 0; r < 4; ++r) {
        otw[l15*68 +  0 + quad*4 + r] = o0[r] * inv;
        otw[l15*68 + 16 + quad*4 + r] = o1[r] * inv;
        otw[l15*68 + 32 + quad*4 + r] = o2[r] * inv;
        otw[l15*68 + 48 + quad*4 + r] = o3[r] * inv;
    }
    asm volatile("s_waitcnt lgkmcnt(0)" ::: "memory");
    int row = lane >> 2, ch = (lane & 3) * 16;
    union { __bf16 hh[16]; uint4 q4[2]; } ob;
    #pragma unroll
    for (int t2 = 0; t2 < 16; ++t2) ob.hh[t2] = f2b(otw[row*68 + ch + t2]);
    __bf16* cp = qkc + (size_t)(b*SS + qrow0 + row) * 1024 + h*64 + ch;
    *(uint4*)cp = ob.q4[0];
    *(uint4*)(cp + 8) = ob.q4[1];
}

// ================= final projection (bf16 h) =================
__global__ __launch_bounds__(256) void proj_kernel(
    const __bf16* __restrict__ h_bf, const float* __restrict__ Wp,
    const float* __restrict__ bp, float* __restrict__ out)
{
    int rid = blockIdx.x * 8 + (threadIdx.x >> 5);
    int col = threadIdx.x & 31;
    int b = rid / TT, i = rid - b * TT;
    const __bf16* x = h_bf + ((size_t)(b*SS) + 3*i + 1) * HDIM;
    float acc = bp[col];
    for (int kk = 0; kk < HDIM; ++kk)
        acc += (float)x[kk] * Wp[kk * ADIM + col];
    out[(size_t)rid * ADIM + col] = acc;
}

extern "C" void kernel_launch(void* const* d_in, const int* in_sizes, int n_in,
                              void* d_out, int out_size, void* d_ws, size_t ws_size,
                              hipStream_t stream)
{
    (void)in_sizes; (void)n_in; (void)out_size; (void)ws_size;
    const int*   timesteps = (const int*)  d_in[0];
    const float* state0    = (const float*)d_in[1];
    const float* state1    = (const float*)d_in[2];
    const float* actions   = (const float*)d_in[3];
    const float* time_emb  = (const float*)d_in[4];
    const float* Ws  = (const float*)d_in[5];
    const float* bs  = (const float*)d_in[6];
    const float* Wa  = (const float*)d_in[7];
    const float* ba  = (const float*)d_in[8];
    const float* Wq  = (const float*)d_in[9];
    const float* bq  = (const float*)d_in[10];
    const float* Wk  = (const float*)d_in[11];
    const float* bk  = (const float*)d_in[12];
    const float* Wv  = (const float*)d_in[13];
    const float* bv  = (const float*)d_in[14];
    const float* Wo  = (const float*)d_in[15];
    const float* bo  = (const float*)d_in[16];
    const float* W1  = (const float*)d_in[17];
    const float* b1  = (const float*)d_in[18];
    const float* W2  = (const float*)d_in[19];
    const float* b2  = (const float*)d_in[20];
    const float* ln1g = (const float*)d_in[21];
    const float* ln1b = (const float*)d_in[22];
    const float* ln2g = (const float*)d_in[23];
    const float* ln2b = (const float*)d_in[24];
    const float* elng = (const float*)d_in[25];
    const float* elnb = (const float*)d_in[26];
    const float* Wp   = (const float*)d_in[27];
    const float* bp   = (const float*)d_in[28];
    float* out = (float*)d_out;

    const size_t SZ = (size_t)MS * HDIM;          // 3,145,728
    char* p = (char*)d_ws;
    __bf16* h_bf = (__bf16*)p;           p += SZ * 2;                  // residual (bf16)
    __bf16* qk   = (__bf16*)p;           p += (size_t)MS * 1024 * 2;   // q|k; q-sec doubles as ctx
    __bf16* VT   = (__bf16*)p;           p += SZ * 2;
    /* hid extension */                  p += SZ * 2;                  // hid = qk..VT..ext (MSx2048)
    __bf16* tmp_bf = (__bf16*)p;         p += SZ * 2;
    __bf16* wqkvT = (__bf16*)p;          p += (size_t)1536 * 512 * 2;
    __bf16* woT   = (__bf16*)p;          p += (size_t)512 * 512 * 2;
    __bf16* w1T   = (__bf16*)p;          p += (size_t)2048 * 512 * 2;
    __bf16* w2T   = (__bf16*)p;          p += (size_t)512 * 2048 * 2;
    float*  biasq = (float*)p;           p += 1536 * 4;
    __bf16* hid   = qk;                  // MS x 2048 bf16 spans qk+VT+ext

    embed_ln_kernel<<<MS, 512, 0, stream>>>(timesteps, state0, state1, actions, time_emb,
                                            Ws, bs, Wa, ba, elng, elnb, h_bf);

    dim3 gQKV(1536/128, MS/128);   // 12 x 48
    dim3 gO  (512/128,  MS/64);    // 4 x 96  (64-row tiles)
    dim3 gF1 (2048/128, MS/128);   // 16 x 48

    for (int lyr = 0; lyr < NBLK; ++lyr) {
        const float* wq = Wq + (size_t)lyr * HDIM * HDIM;
        const float* wk = Wk + (size_t)lyr * HDIM * HDIM;
        const float* wv = Wv + (size_t)lyr * HDIM * HDIM;
        const float* wo = Wo + (size_t)lyr * HDIM * HDIM;
        const float* w1 = W1 + (size_t)lyr * HDIM * DFF;
        const float* w2 = W2 + (size_t)lyr * DFF * HDIM;

        pack_kernel<<<769, 256, 0, stream>>>(wq, wk, wv, wo, w1, w2,
                                             bq + lyr*HDIM, bk + lyr*HDIM, bv + lyr*HDIM,
                                             wqkvT, woT, w1T, w2T, biasq);
        // QKV: q|k rows -> qk (ldc 1024); V tiles transposed -> VT in-epilogue
        gemm_mfma<128, true><<<gQKV, 256, 0, stream>>>(h_bf, wqkvT, biasq, qk, VT,
                                                       1536, HDIM, HDIM, 1024, 0);
        attn_kernel<<<dim3(768), 256, 0, stream>>>(qk, VT);
        // WO: A = ctx (q-section, lda 1024)
        gemm_mfma<64, false><<<gO, 256, 0, stream>>>(qk, woT, bo + lyr*HDIM, tmp_bf, nullptr,
                                                     HDIM, HDIM, 1024, HDIM, 0);
        ln_add_kernel<<<MS, 512, 0, stream>>>(h_bf, tmp_bf, ln1g + lyr*HDIM, ln1b + lyr*HDIM);
        gemm_mfma<128, false><<<gF1, 256, 0, stream>>>(h_bf, w1T, b1 + lyr*DFF, hid, nullptr,
                                                       DFF, HDIM, HDIM, DFF, 1);
        gemm_mfma<64, false><<<gO, 256, 0, stream>>>(hid, w2T, b2 + lyr*HDIM, tmp_bf, nullptr,
                                                     HDIM, DFF, DFF, HDIM, 0);
        ln_add_kernel<<<MS, 512, 0, stream>>>(h_bf, tmp_bf, ln2g + lyr*HDIM, ln2b + lyr*HDIM);
    }

    proj_kernel<<<(BB*TT)/8, 256, 0, stream>>>(h_bf, Wp, bp, out);
}

// Round 11
// 1118.851 us; speedup vs baseline: 1.4876x; 1.0247x over previous
//
#include <hip/hip_runtime.h>
#include <hip/hip_bf16.h>
#include <math.h>

#define BB 4
#define TT 512
#define SDIM 64
#define ADIM 32
#define HDIM 512
#define NH 8
#define NBLK 6
#define DFF 2048
#define SS 1536          // 3*T
#define DH 64
#define MS (BB*SS)       // 6144 rows

typedef __attribute__((ext_vector_type(8))) __bf16 bf16x8;
typedef __attribute__((ext_vector_type(4))) float f32x4;

__device__ __forceinline__ __bf16 f2b(float x) { return (__bf16)x; }

// async global->LDS, 16 B per lane; LDS dest = wave-uniform base + lane*16
__device__ __forceinline__ void gll16(const void* g, void* l) {
    __builtin_amdgcn_global_load_lds(
        (const __attribute__((address_space(1))) unsigned int*)g,
        (__attribute__((address_space(3))) unsigned int*)l, 16, 0, 0);
}

// ================= shuffle-based LN over 512 threads =================
__device__ __forceinline__ float block_ln2(float val, int tid,
                                           const float* __restrict__ g,
                                           const float* __restrict__ bvec,
                                           float* red)
{
    float s = val, sq = val * val;
    #pragma unroll
    for (int off = 32; off; off >>= 1) { s += __shfl_xor(s, off); sq += __shfl_xor(sq, off); }
    int w = tid >> 6;
    if ((tid & 63) == 0) { red[w] = s; red[8 + w] = sq; }
    __syncthreads();
    float S = 0.f, SQ = 0.f;
    #pragma unroll
    for (int i = 0; i < 8; ++i) { S += red[i]; SQ += red[8 + i]; }
    float mean = S * (1.f / HDIM);
    float var  = SQ * (1.f / HDIM) - mean * mean;
    return (val - mean) * rsqrtf(var + 1e-5f) * g[tid] + bvec[tid];
}

// ================= embed + LN -> h_bf (bf16 residual stream) =================
__global__ __launch_bounds__(512) void embed_ln_kernel(
    const int* __restrict__ timesteps,
    const float* __restrict__ state0, const float* __restrict__ state1,
    const float* __restrict__ actions, const float* __restrict__ time_emb,
    const float* __restrict__ Ws, const float* __restrict__ bs,
    const float* __restrict__ Wa, const float* __restrict__ ba,
    const float* __restrict__ eg, const float* __restrict__ eb,
    __bf16* __restrict__ h_bf)
{
    __shared__ float xs[SDIM];
    __shared__ float red[16];
    int row = blockIdx.x;
    int b = row / SS;
    int pos = row - b * SS;
    int i = pos / 3;
    int t = pos - i * 3;
    int col = threadIdx.x;

    const float* x; const float* W; const float* bias; int K;
    if (t == 0)      { x = state0  + (size_t)(b*TT + i) * SDIM; W = Ws; bias = bs; K = SDIM; }
    else if (t == 1) { x = state1  + (size_t)(b*TT + i) * SDIM; W = Ws; bias = bs; K = SDIM; }
    else             { x = actions + (size_t)(b*TT + i) * ADIM; W = Wa; bias = ba; K = ADIM; }

    if (col < K) xs[col] = x[col];
    __syncthreads();

    int ts = timesteps[b*TT + i];
    float acc = bias[col] + time_emb[(size_t)ts * HDIM + col];
    for (int kk = 0; kk < K; ++kk)
        acc += xs[kk] * W[(size_t)kk * HDIM + col];

    float y = block_ln2(acc, col, eg, eb, red);
    h_bf[(size_t)row * HDIM + col] = f2b(y);
}

// ================= residual add (two bf16 partials) + LN =================
__global__ __launch_bounds__(512) void ln_add2_kernel(
    __bf16* __restrict__ h_bf, const __bf16* __restrict__ ya,
    const __bf16* __restrict__ yb,
    const float* __restrict__ g, const float* __restrict__ bvec)
{
    __shared__ float red[16];
    int row = blockIdx.x, col = threadIdx.x;
    size_t idx = (size_t)row * HDIM + col;
    float val = (float)h_bf[idx] + (float)ya[idx] + (float)yb[idx];
    float o = block_ln2(val, col, g, bvec, red);
    h_bf[idx] = f2b(o);
}

// ================= weight pack: fp32 [K][N] -> bf16 [N][K] =================
__global__ __launch_bounds__(256) void pack_kernel(
    const float* __restrict__ wq, const float* __restrict__ wk,
    const float* __restrict__ wv, const float* __restrict__ wo,
    const float* __restrict__ w1, const float* __restrict__ w2,
    const float* __restrict__ bq_, const float* __restrict__ bk_, const float* __restrict__ bv_,
    __bf16* __restrict__ wqkvT, __bf16* __restrict__ woT,
    __bf16* __restrict__ w1T, __bf16* __restrict__ w2T, float* __restrict__ biasq)
{
    int bid = blockIdx.x;
    int tid = threadIdx.x;
    if (bid == 768) {
        for (int i = tid; i < 1536; i += 256)
            biasq[i] = (i < 512) ? bq_[i] : ((i < 1024) ? bk_[i-512] : bv_[i-1024]);
        return;
    }
    __shared__ float Ls[64][65];
    const float* src; __bf16* dst; int K, N, kt, nt;
    if (bid < 192) {
        int sec = bid / 64, t = bid % 64;
        src = (sec == 0) ? wq : (sec == 1) ? wk : wv;
        dst = wqkvT + (size_t)sec * 512 * 512;
        K = 512; N = 512; nt = t >> 3; kt = t & 7;
    } else if (bid < 256) {
        int t = bid - 192; src = wo; dst = woT; K = 512; N = 512; nt = t >> 3; kt = t & 7;
    } else if (bid < 512) {
        int t = bid - 256; src = w1; dst = w1T; K = 512; N = 2048; nt = t >> 3; kt = t & 7;
    } else {
        int t = bid - 512; src = w2; dst = w2T; K = 2048; N = 512; nt = t & 7; kt = t >> 3;
    }
    int k0 = kt * 64, n0 = nt * 64;
    int rr = tid >> 4, cc = (tid & 15) * 4;
    #pragma unroll
    for (int p = 0; p < 4; ++p) {
        float4 v = *(const float4*)(src + (size_t)(k0 + rr + p*16) * N + n0 + cc);
        Ls[rr + p*16][cc] = v.x; Ls[rr + p*16][cc+1] = v.y;
        Ls[rr + p*16][cc+2] = v.z; Ls[rr + p*16][cc+3] = v.w;
    }
    __syncthreads();
    int nn = tid >> 3, kc = (tid & 7) * 8;
    #pragma unroll
    for (int p = 0; p < 2; ++p) {
        __bf16 t8[8];
        #pragma unroll
        for (int t2 = 0; t2 < 8; ++t2) t8[t2] = f2b(Ls[kc + t2][nn + p*32]);
        *(uint4*)(dst + (size_t)(n0 + nn + p*32) * K + k0 + kc) = *(uint4*)t8;
    }
}

// ================= bf16 MFMA GEMM, double-buffered async LDS staging =================
// A: bf16 [M][lda].  Bt: bf16 [N][ldb].  C: bf16 [M][ldc].
// Split-K via blockIdx.z: k-range [z*Ksub, (z+1)*Ksub); C += z*cSplitStride;
// bias applied only on z==0.
// VTMODE: blocks with n0 >= 1024 write their tile TRANSPOSED to VTout.
template<int MT, bool VTMODE>
__global__ __launch_bounds__(256) void gemm_mfma(
    const __bf16* __restrict__ A, const __bf16* __restrict__ Bt,
    const float* __restrict__ bias, __bf16* __restrict__ C,
    __bf16* __restrict__ VTout,
    int N, int Ksub, int lda, int ldb, int ldc, int gelu, size_t cSplitStride)
{
    constexpr int MI = MT / 32;
    constexpr int SMB = 2*MT*64 + 2*128*64;
    __shared__ __align__(16) char sm[SMB];
    __bf16* As = (__bf16*)sm;                    // [2][MT][32]
    __bf16* Bs = (__bf16*)(sm + 2*MT*64);        // [2][128][32]
    int tid = threadIdx.x;
    int wave = tid >> 6, lane = tid & 63;
    int l15 = lane & 15, quad = lane >> 4;
    int wy = wave >> 1, wx = wave & 1;
    int m0 = blockIdx.y * MT, n0 = blockIdx.x * 128;
    int zs = blockIdx.z;
    int kbase = zs * Ksub;
    C += (size_t)zs * cSplitStride;

    int srow = lane >> 2;
    int clog = (lane & 3) ^ ((lane >> 3) & 3);
    int pchunk = (quad ^ ((l15 >> 1) & 3)) * 8;

    f32x4 acc[MI][4];
    #pragma unroll
    for (int i = 0; i < MI; ++i)
        #pragma unroll
        for (int j = 0; j < 4; ++j) acc[i][j] = (f32x4){0.f,0.f,0.f,0.f};

    const __bf16* Abase = A  + (size_t)m0 * lda + kbase + clog * 8;
    const __bf16* Bbase = Bt + (size_t)n0 * ldb + kbase + clog * 8;
    int NK = Ksub >> 5;

    // prologue: stage k-tile 0 into buffer 0
    #pragma unroll
    for (int q = 0; q < MT/64; ++q) {
        int r0 = (wave * (MT/64) + q) * 16;
        gll16(Abase + (size_t)(r0 + srow) * lda, As + r0*32);
    }
    #pragma unroll
    for (int q = 0; q < 2; ++q) {
        int r0 = (wave * 2 + q) * 16;
        gll16(Bbase + (size_t)(r0 + srow) * ldb, Bs + r0*32);
    }

    for (int kt = 0; kt < NK; ++kt) {
        int buf = kt & 1;
        __syncthreads();   // drains the loads for `buf` (issued one full iter ago)
        if (kt + 1 < NK) {
            int k0 = (kt + 1) << 5;
            #pragma unroll
            for (int q = 0; q < MT/64; ++q) {
                int r0 = (wave * (MT/64) + q) * 16;
                gll16(Abase + (size_t)(r0 + srow) * lda + k0, As + ((buf^1)*MT + r0)*32);
            }
            #pragma unroll
            for (int q = 0; q < 2; ++q) {
                int r0 = (wave * 2 + q) * 16;
                gll16(Bbase + (size_t)(r0 + srow) * ldb + k0, Bs + ((buf^1)*128 + r0)*32);
            }
        }
        bf16x8 af[MI], bf[4];
        #pragma unroll
        for (int i = 0; i < MI; ++i)
            af[i] = *(const bf16x8*)&As[(buf*MT + wy*(MT/2) + i*16 + l15)*32 + pchunk];
        #pragma unroll
        for (int j = 0; j < 4; ++j)
            bf[j] = *(const bf16x8*)&Bs[(buf*128 + wx*64 + j*16 + l15)*32 + pchunk];
        #pragma unroll
        for (int i = 0; i < MI; ++i)
            #pragma unroll
            for (int j = 0; j < 4; ++j)
                acc[i][j] = __builtin_amdgcn_mfma_f32_16x16x32_bf16(af[i], bf[j], acc[i][j], 0, 0, 0);
    }

    if (VTMODE && n0 >= 1024) {
        // transpose tile (128 s x 128 d) into VT via LDS (reuse staging, 32 KB)
        __syncthreads();
        __bf16* T = (__bf16*)sm;          // logical [128 d][128 s], s-chunk swizzled
        #pragma unroll
        for (int j = 0; j < 4; ++j) {
            int dl = wx*64 + j*16 + l15;
            float bv = bias[n0 + dl];
            int x31 = dl & 31;
            #pragma unroll
            for (int i = 0; i < MI; ++i) {
                int sc = wy*16 + i*4 + quad;          // 4-elem s-chunk index
                int phys = sc ^ x31;
                __bf16 v4[4];
                #pragma unroll
                for (int r = 0; r < 4; ++r) v4[r] = f2b(acc[i][j][r] + bv);
                *(uint2*)(T + dl*128 + phys*4) = *(uint2*)v4;
            }
        }
        __syncthreads();
        int dl = tid >> 1, sh = (tid & 1) * 64;
        int dglob = n0 - 1024 + dl;
        int bb = m0 / SS, srel = m0 - bb*SS;
        __bf16* vb = VTout + ((size_t)(bb*NH + (dglob >> 6)) * 64 + (dglob & 63)) * SS + srel + sh;
        int x31 = dl & 31;
        #pragma unroll
        for (int u = 0; u < 8; ++u) {
            int c0 = (sh >> 2) + u*2;
            uint2 lo = *(const uint2*)(T + dl*128 + ((c0    ) ^ x31)*4);
            uint2 hi = *(const uint2*)(T + dl*128 + ((c0 + 1) ^ x31)*4);
            uint4 o; o.x = lo.x; o.y = lo.y; o.z = hi.x; o.w = hi.y;
            *(uint4*)(vb + u*8) = o;
        }
        return;
    }

    #pragma unroll
    for (int j = 0; j < 4; ++j) {
        int cc = n0 + wx*64 + j*16 + l15;
        float bv = (zs == 0) ? bias[cc] : 0.f;
        #pragma unroll
        for (int i = 0; i < MI; ++i) {
            #pragma unroll
            for (int r = 0; r < 4; ++r) {
                int rr = m0 + wy*(MT/2) + i*16 + quad*4 + r;
                float v = acc[i][j][r] + bv;
                if (gelu) v = 0.5f * v * (1.f + erff(v * 0.70710678118654752f));
                C[(size_t)rr * ldc + cc] = f2b(v);
            }
        }
    }
}

// ================= S^T-layout MFMA flash attention, 64-row K-tiles =================
#define SM_C 0.18033688011112042f   // (1/8) * log2(e)

__device__ __forceinline__ unsigned pack2bf(float a, float b)
{
    union { __bf16 h[2]; unsigned u; } t;
    t.h[0] = (__bf16)a; t.h[1] = (__bf16)b;
    return t.u;
}

// P^T (two 16-row frags) -> PV B-frag. All shuffles at full wave exec,
// per-lane cndmask after (verified in rounds 4-10).
__device__ __forceinline__ bf16x8 ptrans(const float* p0, const float* p1, int lane)
{
    int l15 = lane & 15, quad = lane >> 4;
    unsigned pk0a = pack2bf(p0[0], p0[1]), pk0b = pack2bf(p0[2], p0[3]);
    unsigned pk1a = pack2bf(p1[0], p1[1]), pk1b = pack2bf(p1[2], p1[3]);
    int sA = l15 + (quad & 1) * 32;
    int sB = sA + 16;
    int hi = quad >> 1;
    unsigned a0A = (unsigned)__shfl((int)pk0a, sA);
    unsigned a1A = (unsigned)__shfl((int)pk1a, sA);
    unsigned b0A = (unsigned)__shfl((int)pk0b, sA);
    unsigned b1A = (unsigned)__shfl((int)pk1b, sA);
    unsigned a0B = (unsigned)__shfl((int)pk0a, sB);
    unsigned a1B = (unsigned)__shfl((int)pk1a, sB);
    unsigned b0B = (unsigned)__shfl((int)pk0b, sB);
    unsigned b1B = (unsigned)__shfl((int)pk1b, sB);
    union { unsigned u[4]; bf16x8 v; } pb;
    pb.u[0] = hi ? a1A : a0A;
    pb.u[1] = hi ? b1A : b0A;
    pb.u[2] = hi ? a1B : a0B;
    pb.u[3] = hi ? b1B : b0B;
    return pb.v;
}

// grid: 768 blocks (region-interleaved qt), 256 threads; block shares K/V via LDS.
// qkc: [row][1024] = q|k; ctx overwrites the q-section (disjoint ownership).
// LDS (32 KB): K tile [64 s][64 d] x2 bufs, V^T tile [64 d][64 s] x2,
// chunk-swizzled phys = c ^ (row & 7). nkt = qt+1, uniform across waves.
__global__ __launch_bounds__(256, 3) void attn_kernel(
    __bf16* qkc, const __bf16* __restrict__ VT)
{
    __shared__ __align__(16) char smem[32768];

    int x = blockIdx.x;
    int region = x >> 8;          // 0,1,2
    int j = x & 255;
    int i = j >> 5;               // 0..7
    int hb = j & 31;
    int qt = (region == 0) ? i : (region == 1) ? (15 - i) : (16 + i);
    int h = hb >> 2, b = hb & 3;

    int tid = threadIdx.x;
    int w = tid >> 6, lane = tid & 63;
    int l15 = lane & 15, quad = lane >> 4;
    int qrow0 = qt * 64 + w * 16;

    const __bf16* qp = qkc + (size_t)(b*SS + qrow0 + l15) * 1024 + h*64 + quad*8;
    bf16x8 qf0 = *(const bf16x8*)qp;
    bf16x8 qf1 = *(const bf16x8*)(qp + 32);

    // staging bases
    const __bf16* kgbase = qkc + (size_t)(b*SS) * 1024 + 512 + h*64;     // + srow*1024
    const __bf16* vgbase = VT + (size_t)(b*NH + h) * 64 * SS;            // + drow*SS
    int srow8 = lane >> 3;                        // 0..7
    int clog  = (lane & 7) ^ ((lane >> 3) & 7);   // logical chunk for DMA lane
    int sw0 = ((0*4 + quad) ^ (l15 & 7)) * 8;
    int sw1 = ((1*4 + quad) ^ (l15 & 7)) * 8;

    f32x4 o0 = {0.f,0.f,0.f,0.f}, o1 = o0, o2 = o0, o3 = o0;
    float sm_m = -1e30f, sm_l = 0.f;

    int nkt = qt + 1;

    #pragma unroll
    for (int q = 0; q < 2; ++q) {
        int r0 = (w*2 + q) * 8;
        gll16(kgbase + (size_t)(r0 + srow8) * 1024 + clog*8, (__bf16*)smem + r0*64);
        gll16(vgbase + (size_t)(r0 + srow8) * SS   + clog*8, (__bf16*)(smem + 16384) + r0*64);
    }
    __syncthreads();

    for (int jt = 0; jt < nkt; ++jt) {
        int buf = jt & 1;
        const __bf16* Kb = (const __bf16*)(smem + buf * 8192);
        const __bf16* Vb = (const __bf16*)(smem + 16384 + buf * 8192);
        if (jt + 1 < nkt) {
            int kb2 = (jt + 1) * 64;
            __bf16* Kn = (__bf16*)(smem + (buf ^ 1) * 8192);
            __bf16* Vn = (__bf16*)(smem + 16384 + (buf ^ 1) * 8192);
            #pragma unroll
            for (int q = 0; q < 2; ++q) {
                int r0 = (w*2 + q) * 8;
                gll16(kgbase + (size_t)(kb2 + r0 + srow8) * 1024 + clog*8, Kn + r0*64);
                gll16(vgbase + (size_t)(r0 + srow8) * SS + kb2 + clog*8,   Vn + r0*64);
            }
        }
        int kb = jt * 64;

        f32x4 s[4];
        #pragma unroll
        for (int f = 0; f < 4; ++f) {
            bf16x8 k0 = *(const bf16x8*)(Kb + (16*f + l15)*64 + sw0);
            bf16x8 k1 = *(const bf16x8*)(Kb + (16*f + l15)*64 + sw1);
            f32x4 sf = {0.f,0.f,0.f,0.f};
            sf = __builtin_amdgcn_mfma_f32_16x16x32_bf16(k0, qf0, sf, 0, 0, 0);
            sf = __builtin_amdgcn_mfma_f32_16x16x32_bf16(k1, qf1, sf, 0, 0, 0);
            s[f] = sf;
        }

        if (kb + 63 > qrow0) {
            int qrow = qrow0 + l15;
            #pragma unroll
            for (int f = 0; f < 4; ++f)
                #pragma unroll
                for (int r = 0; r < 4; ++r)
                    if (kb + 16*f + quad*4 + r > qrow) s[f][r] = -1e30f;
        }

        float tm = -1e30f;
        #pragma unroll
        for (int f = 0; f < 4; ++f)
            #pragma unroll
            for (int r = 0; r < 4; ++r) tm = fmaxf(tm, s[f][r]);
        tm = fmaxf(tm, __shfl_xor(tm, 16));
        tm = fmaxf(tm, __shfl_xor(tm, 32));
        float mnew = fmaxf(sm_m, tm);
        float alpha = __builtin_amdgcn_exp2f((sm_m - mnew) * SM_C);

        float pp[4][4];
        float rs = 0.f;
        #pragma unroll
        for (int f = 0; f < 4; ++f)
            #pragma unroll
            for (int r = 0; r < 4; ++r) {
                float pv = __builtin_amdgcn_exp2f((s[f][r] - mnew) * SM_C);
                pp[f][r] = pv;
                rs += pv;
            }
        rs += __shfl_xor(rs, 16);
        rs += __shfl_xor(rs, 32);
        sm_l = sm_l * alpha + rs;
        sm_m = mnew;
        o0 *= alpha; o1 *= alpha; o2 *= alpha; o3 *= alpha;

        bf16x8 pb01 = ptrans(pp[0], pp[1], lane);
        bf16x8 pb23 = ptrans(pp[2], pp[3], lane);

        #pragma unroll
        for (int ii = 0; ii < 4; ++ii) {
            bf16x8 va = *(const bf16x8*)(Vb + (16*ii + l15)*64 + sw0);
            bf16x8 vb = *(const bf16x8*)(Vb + (16*ii + l15)*64 + sw1);
            f32x4* op = (ii == 0) ? &o0 : (ii == 1) ? &o1 : (ii == 2) ? &o2 : &o3;
            *op = __builtin_amdgcn_mfma_f32_16x16x32_bf16(va, pb01, *op, 0, 0, 0);
            *op = __builtin_amdgcn_mfma_f32_16x16x32_bf16(vb, pb23, *op, 0, 0, 0);
        }
        __syncthreads();
    }

    // epilogue: O^T regs -> LDS -> coalesced bf16 stores
    float* otw = (float*)smem + w * 16 * 68;
    float inv = 1.f / sm_l;
    #pragma unroll
    for (int r = 0; r < 4; ++r) {
        otw[l15*68 +  0 + quad*4 + r] = o0[r] * inv;
        otw[l15*68 + 16 + quad*4 + r] = o1[r] * inv;
        otw[l15*68 + 32 + quad*4 + r] = o2[r] * inv;
        otw[l15*68 + 48 + quad*4 + r] = o3[r] * inv;
    }
    asm volatile("s_waitcnt lgkmcnt(0)" ::: "memory");
    int row = lane >> 2, ch = (lane & 3) * 16;
    union { __bf16 hh[16]; uint4 q4[2]; } ob;
    #pragma unroll
    for (int t2 = 0; t2 < 16; ++t2) ob.hh[t2] = f2b(otw[row*68 + ch + t2]);
    __bf16* cp = qkc + (size_t)(b*SS + qrow0 + row) * 1024 + h*64 + ch;
    *(uint4*)cp = ob.q4[0];
    *(uint4*)(cp + 8) = ob.q4[1];
}

// ================= final projection (bf16 h) =================
__global__ __launch_bounds__(256) void proj_kernel(
    const __bf16* __restrict__ h_bf, const float* __restrict__ Wp,
    const float* __restrict__ bp, float* __restrict__ out)
{
    int rid = blockIdx.x * 8 + (threadIdx.x >> 5);
    int col = threadIdx.x & 31;
    int b = rid / TT, i = rid - b * TT;
    const __bf16* x = h_bf + ((size_t)(b*SS) + 3*i + 1) * HDIM;
    float acc = bp[col];
    for (int kk = 0; kk < HDIM; ++kk)
        acc += (float)x[kk] * Wp[kk * ADIM + col];
    out[(size_t)rid * ADIM + col] = acc;
}

extern "C" void kernel_launch(void* const* d_in, const int* in_sizes, int n_in,
                              void* d_out, int out_size, void* d_ws, size_t ws_size,
                              hipStream_t stream)
{
    (void)in_sizes; (void)n_in; (void)out_size; (void)ws_size;
    const int*   timesteps = (const int*)  d_in[0];
    const float* state0    = (const float*)d_in[1];
    const float* state1    = (const float*)d_in[2];
    const float* actions   = (const float*)d_in[3];
    const float* time_emb  = (const float*)d_in[4];
    const float* Ws  = (const float*)d_in[5];
    const float* bs  = (const float*)d_in[6];
    const float* Wa  = (const float*)d_in[7];
    const float* ba  = (const float*)d_in[8];
    const float* Wq  = (const float*)d_in[9];
    const float* bq  = (const float*)d_in[10];
    const float* Wk  = (const float*)d_in[11];
    const float* bk  = (const float*)d_in[12];
    const float* Wv  = (const float*)d_in[13];
    const float* bv  = (const float*)d_in[14];
    const float* Wo  = (const float*)d_in[15];
    const float* bo  = (const float*)d_in[16];
    const float* W1  = (const float*)d_in[17];
    const float* b1  = (const float*)d_in[18];
    const float* W2  = (const float*)d_in[19];
    const float* b2  = (const float*)d_in[20];
    const float* ln1g = (const float*)d_in[21];
    const float* ln1b = (const float*)d_in[22];
    const float* ln2g = (const float*)d_in[23];
    const float* ln2b = (const float*)d_in[24];
    const float* elng = (const float*)d_in[25];
    const float* elnb = (const float*)d_in[26];
    const float* Wp   = (const float*)d_in[27];
    const float* bp   = (const float*)d_in[28];
    float* out = (float*)d_out;

    const size_t SZ = (size_t)MS * HDIM;          // 3,145,728
    char* p = (char*)d_ws;
    __bf16* h_bf = (__bf16*)p;           p += SZ * 2;                  // residual (bf16)
    __bf16* qk   = (__bf16*)p;           p += (size_t)MS * 1024 * 2;   // q|k; q-sec doubles as ctx
    __bf16* VT   = (__bf16*)p;           p += SZ * 2;
    /* hid extension */                  p += SZ * 2;                  // hid = qk..VT..ext (MSx2048)
    __bf16* tmpA = (__bf16*)p;           p += SZ * 2;                  // split-K partial 0
    __bf16* tmpB = (__bf16*)p;           p += SZ * 2;                  // split-K partial 1
    __bf16* wqkvT = (__bf16*)p;          p += (size_t)1536 * 512 * 2;
    __bf16* woT   = (__bf16*)p;          p += (size_t)512 * 512 * 2;
    __bf16* w1T   = (__bf16*)p;          p += (size_t)2048 * 512 * 2;
    __bf16* w2T   = (__bf16*)p;          p += (size_t)512 * 2048 * 2;
    float*  biasq = (float*)p;           p += 1536 * 4;
    __bf16* hid   = qk;                  // MS x 2048 bf16 spans qk+VT+ext

    embed_ln_kernel<<<MS, 512, 0, stream>>>(timesteps, state0, state1, actions, time_emb,
                                            Ws, bs, Wa, ba, elng, elnb, h_bf);

    dim3 gQKV(1536/128, MS/128, 1);    // 12 x 48
    dim3 gO  (512/128,  MS/64, 2);     // 4 x 96 x 2  (split-K)
    dim3 gF1 (2048/128, MS/128, 1);    // 16 x 48

    for (int lyr = 0; lyr < NBLK; ++lyr) {
        const float* wq = Wq + (size_t)lyr * HDIM * HDIM;
        const float* wk = Wk + (size_t)lyr * HDIM * HDIM;
        const float* wv = Wv + (size_t)lyr * HDIM * HDIM;
        const float* wo = Wo + (size_t)lyr * HDIM * HDIM;
        const float* w1 = W1 + (size_t)lyr * HDIM * DFF;
        const float* w2 = W2 + (size_t)lyr * DFF * HDIM;

        pack_kernel<<<769, 256, 0, stream>>>(wq, wk, wv, wo, w1, w2,
                                             bq + lyr*HDIM, bk + lyr*HDIM, bv + lyr*HDIM,
                                             wqkvT, woT, w1T, w2T, biasq);
        // QKV: q|k rows -> qk (ldc 1024); V tiles transposed -> VT in-epilogue
        gemm_mfma<128, true><<<gQKV, 256, 0, stream>>>(h_bf, wqkvT, biasq, qk, VT,
                                                       1536, 512, 512, 512, 1024, 0, 0);
        attn_kernel<<<dim3(768), 256, 0, stream>>>(qk, VT);
        // WO: A = ctx (q-section, lda 1024); split-K=2 (256 each)
        gemm_mfma<64, false><<<gO, 256, 0, stream>>>(qk, woT, bo + lyr*HDIM, tmpA, nullptr,
                                                     512, 256, 1024, 512, 512, 0, SZ);
        ln_add2_kernel<<<MS, 512, 0, stream>>>(h_bf, tmpA, tmpB, ln1g + lyr*HDIM, ln1b + lyr*HDIM);
        gemm_mfma<128, false><<<gF1, 256, 0, stream>>>(h_bf, w1T, b1 + lyr*DFF, hid, nullptr,
                                                       2048, 512, 512, 512, 2048, 1, 0);
        // W2: split-K=2 (1024 each)
        gemm_mfma<64, false><<<gO, 256, 0, stream>>>(hid, w2T, b2 + lyr*HDIM, tmpA, nullptr,
                                                     512, 1024, 2048, 2048, 512, 0, SZ);
        ln_add2_kernel<<<MS, 512, 0, stream>>>(h_bf, tmpA, tmpB, ln2g + lyr*HDIM, ln2b + lyr*HDIM);
    }

    proj_kernel<<<(BB*TT)/8, 256, 0, stream>>>(h_bf, Wp, bp, out);
}